// Round 1
// baseline (471.157 us; speedup 1.0000x reference)
//
#include <hip/hip_runtime.h>
#include <hip/hip_bf16.h>

typedef __bf16 bf16_t;
typedef __bf16 bf16x8 __attribute__((ext_vector_type(8)));
typedef float f32x4 __attribute__((ext_vector_type(4)));

constexpr int E  = 1024;
constexpr int NH = 16;
constexpr int HD = 64;
constexpr int NB = 2;
constexpr int GS = 48;          // spatial side
constexpr int L  = GS * GS;     // 2304 tokens per batch
constexpr int T  = NB * L;      // 4608 tokens
constexpr int BH = NB * NH;     // 32 batch*head

// ---------------- xpos tables: [4][48][16] = cs_q, ss_q, cs_k, ss_k ----------------
__global__ void xpos_tables_kernel(float* __restrict__ tabs) {
    int i = threadIdx.x;
    if (i >= GS * 16) return;
    int p = i >> 4, j = i & 15;
    // scale_vec = (2j + 0.4*32)/(1.4*32); power = (p - 24)/512
    float sv = (2.0f * (float)j + 12.8f) / 44.8f;
    float pw = ((float)p - 24.0f) / 512.0f;
    float scale = powf(sv, pw);
    float inv_freq = powf(10000.0f, -(float)j / 16.0f);
    float ang = (float)p * inv_freq;
    float s = sinf(ang), c = cosf(ang);
    tabs[0 * 768 + i] = c * scale;   // q: downscale=False
    tabs[1 * 768 + i] = s * scale;
    tabs[2 * 768 + i] = c / scale;   // k: downscale=True
    tabs[3 * 768 + i] = s / scale;
}

// ---------------- GEMM: out[t][o] = sum_i A[t][i] * W[o][i] (+bias, mode epilogue) --
// MODE 0: Q -> q_ws[bh][l][d] bf16, scaled 0.125
// MODE 1: K -> k_ws[bh][l][d] bf16
// MODE 2: V -> v_ws[bh][l][d] bf16
// MODE 3: O -> d_out[t][o] fp32
template<int MODE>
__global__ __launch_bounds__(256, 2)
void gemm_kernel(const float* __restrict__ A, const float* __restrict__ W,
                 const float* __restrict__ bias, void* __restrict__ outp)
{
    __shared__ bf16_t As[128 * 64];
    __shared__ bf16_t Bs[128 * 64];
    const int tid = threadIdx.x;
    const int lane = tid & 63;
    const int wv = tid >> 6;
    const int wm = wv >> 1, wn = wv & 1;
    const int lr = lane & 15, lg = lane >> 4;
    const int bm = blockIdx.x, bn = blockIdx.y;

    f32x4 acc[4][4] = {};

    for (int kt = 0; kt < E / 64; ++kt) {
        const int k0 = kt * 64;
        __syncthreads();
        #pragma unroll
        for (int it = 0; it < 4; ++it) {
            int ci = it * 256 + tid;      // 0..1023 : 128 rows x 8 chunks(8 elem)
            int row = ci >> 3, c = ci & 7;
            int sw = ((c ^ (row & 7)) * 8);   // 16B-chunk XOR swizzle
            const float* srcA = A + (size_t)(bm * 128 + row) * E + k0 + c * 8;
            f32x4 a0 = *reinterpret_cast<const f32x4*>(srcA);
            f32x4 a1 = *reinterpret_cast<const f32x4*>(srcA + 4);
            bf16x8 ha;
            ha[0] = (bf16_t)a0[0]; ha[1] = (bf16_t)a0[1]; ha[2] = (bf16_t)a0[2]; ha[3] = (bf16_t)a0[3];
            ha[4] = (bf16_t)a1[0]; ha[5] = (bf16_t)a1[1]; ha[6] = (bf16_t)a1[2]; ha[7] = (bf16_t)a1[3];
            *reinterpret_cast<bf16x8*>(&As[row * 64 + sw]) = ha;
            const float* srcB = W + (size_t)(bn * 128 + row) * E + k0 + c * 8;
            f32x4 b0 = *reinterpret_cast<const f32x4*>(srcB);
            f32x4 b1 = *reinterpret_cast<const f32x4*>(srcB + 4);
            bf16x8 hb;
            hb[0] = (bf16_t)b0[0]; hb[1] = (bf16_t)b0[1]; hb[2] = (bf16_t)b0[2]; hb[3] = (bf16_t)b0[3];
            hb[4] = (bf16_t)b1[0]; hb[5] = (bf16_t)b1[1]; hb[6] = (bf16_t)b1[2]; hb[7] = (bf16_t)b1[3];
            *reinterpret_cast<bf16x8*>(&Bs[row * 64 + sw]) = hb;
        }
        __syncthreads();
        #pragma unroll
        for (int kk = 0; kk < 2; ++kk) {
            bf16x8 af[4], bfr[4];
            #pragma unroll
            for (int m = 0; m < 4; ++m) {
                int row = wm * 64 + m * 16 + lr;
                af[m] = *reinterpret_cast<const bf16x8*>(&As[row * 64 + (((kk * 4 + lg) ^ (row & 7)) * 8)]);
            }
            #pragma unroll
            for (int n = 0; n < 4; ++n) {
                int row = wn * 64 + n * 16 + lr;
                bfr[n] = *reinterpret_cast<const bf16x8*>(&Bs[row * 64 + (((kk * 4 + lg) ^ (row & 7)) * 8)]);
            }
            #pragma unroll
            for (int m = 0; m < 4; ++m)
                #pragma unroll
                for (int n = 0; n < 4; ++n)
                    acc[m][n] = __builtin_amdgcn_mfma_f32_16x16x32_bf16(af[m], bfr[n], acc[m][n], 0, 0, 0);
        }
    }

    #pragma unroll
    for (int m = 0; m < 4; ++m) {
        #pragma unroll
        for (int n = 0; n < 4; ++n) {
            const int col = bn * 128 + wn * 64 + n * 16 + lr;
            const float bv = bias[col];
            #pragma unroll
            for (int r = 0; r < 4; ++r) {
                const int rowg = bm * 128 + wm * 64 + m * 16 + lg * 4 + r;
                float v = acc[m][n][r] + bv;
                if (MODE == 0) v *= 0.125f;
                if (MODE <= 2) {
                    const int nb = rowg / L, ll = rowg % L;
                    const int head = col >> 6, d = col & 63;
                    const int bh = nb * NH + head;
                    ((bf16_t*)outp)[((size_t)bh * L + ll) * HD + d] = (bf16_t)v;
                } else {
                    ((float*)outp)[(size_t)rowg * E + col] = v;
                }
            }
        }
    }
}

// ---------------- xpos apply (in-place on q_ws, k_ws) ----------------
__global__ __launch_bounds__(256)
void xpos_apply_kernel(bf16_t* __restrict__ q_ws, bf16_t* __restrict__ k_ws,
                       const float* __restrict__ tabs)
{
    int idx = blockIdx.x * blockDim.x + threadIdx.x;
    if (idx >= BH * L) return;
    int l = idx % L;
    int y = l / GS, x = l - y * GS;
    const float* csq = tabs;
    const float* ssq = tabs + 768;
    const float* csk = tabs + 1536;
    const float* ssk = tabs + 2304;
    bf16x8* qv = reinterpret_cast<bf16x8*>(q_ws + (size_t)idx * HD);
    bf16x8* kv = reinterpret_cast<bf16x8*>(k_ws + (size_t)idx * HD);
    #pragma unroll
    for (int c = 0; c < 8; ++c) {
        const int half = c >> 2;           // 0: ch 0..31 (x-pos), 1: ch 32..63 (y-pos)
        const int pos = half ? y : x;
        bf16x8 vq = qv[c], vk = kv[c], oq, ok;
        #pragma unroll
        for (int m = 0; m < 4; ++m) {
            const int j = (c & 3) * 4 + m;
            float cs = csq[pos * 16 + j], ss = ssq[pos * 16 + j];
            float e0 = (float)vq[2 * m], e1 = (float)vq[2 * m + 1];
            oq[2 * m]     = (bf16_t)(e0 * cs - e1 * ss);
            oq[2 * m + 1] = (bf16_t)(e1 * cs + e0 * ss);
            cs = csk[pos * 16 + j]; ss = ssk[pos * 16 + j];
            e0 = (float)vk[2 * m]; e1 = (float)vk[2 * m + 1];
            ok[2 * m]     = (bf16_t)(e0 * cs - e1 * ss);
            ok[2 * m + 1] = (bf16_t)(e1 * cs + e0 * ss);
        }
        qv[c] = oq; kv[c] = ok;
    }
}

// ---------------- V transpose: [bh][l][d] -> [bh][d][l] ----------------
__global__ __launch_bounds__(256)
void v_transpose_kernel(const bf16_t* __restrict__ v_ws, bf16_t* __restrict__ vT_ws)
{
    __shared__ bf16_t tile[64][72];
    const int bh = blockIdx.y;
    const int lt = blockIdx.x;       // 0..35
    const int tid = threadIdx.x;
    #pragma unroll
    for (int it = 0; it < 2; ++it) {
        int ci = it * 256 + tid;     // 0..511 : 64 rows x 8 chunks
        int row = ci >> 3, c = ci & 7;
        bf16x8 v = *reinterpret_cast<const bf16x8*>(v_ws + ((size_t)bh * L + lt * 64 + row) * HD + c * 8);
        #pragma unroll
        for (int e = 0; e < 8; ++e) tile[row][c * 8 + e] = v[e];
    }
    __syncthreads();
    #pragma unroll
    for (int it = 0; it < 2; ++it) {
        int ci = it * 256 + tid;
        int d = ci >> 3, c = ci & 7;
        bf16x8 v;
        #pragma unroll
        for (int e = 0; e < 8; ++e) v[e] = tile[c * 8 + e][d];
        *reinterpret_cast<bf16x8*>(vT_ws + ((size_t)bh * HD + d) * L + lt * 64 + c * 8) = v;
    }
}

// ---------------- flash attention ----------------
// grid (L/64, BH), 256 threads = 4 independent waves; wave handles 16 query rows.
__global__ __launch_bounds__(256, 2)
void attn_kernel(const bf16_t* __restrict__ q_ws, const bf16_t* __restrict__ k_ws,
                 const bf16_t* __restrict__ vT_ws, float* __restrict__ attn_out)
{
    __shared__ bf16_t P_lds[4][16][72];   // per-wave, padded rows (144B, 16B aligned)
    const int tid = threadIdx.x;
    const int lane = tid & 63, w = tid >> 6;
    const int lr = lane & 15, lg = lane >> 4;
    const int bh = blockIdx.y;
    const int q0 = blockIdx.x * 64 + w * 16;
    const int nb = bh >> 4, head = bh & 15;

    const bf16_t* qbase = q_ws + (size_t)bh * L * HD;
    const bf16_t* kbase = k_ws + (size_t)bh * L * HD;
    const bf16_t* vbase = vT_ws + (size_t)bh * HD * L;

    bf16x8 qf[2];
    #pragma unroll
    for (int kk = 0; kk < 2; ++kk)
        qf[kk] = *reinterpret_cast<const bf16x8*>(qbase + (size_t)(q0 + lr) * HD + kk * 32 + lg * 8);

    f32x4 o_acc[4] = {};
    float m_run[4], l_run[4];
    #pragma unroll
    for (int r = 0; r < 4; ++r) { m_run[r] = -1e30f; l_run[r] = 0.0f; }

    for (int kt = 0; kt < L / 64; ++kt) {
        // S = Q K^T : 16 q x 64 keys  (C layout: col=key=lane&15, row=q=lg*4+r)
        f32x4 s[4];
        #pragma unroll
        for (int ct = 0; ct < 4; ++ct) {
            const bf16_t* kb = kbase + (size_t)(kt * 64 + ct * 16 + lr) * HD;
            bf16x8 kf0 = *reinterpret_cast<const bf16x8*>(kb + lg * 8);
            bf16x8 kf1 = *reinterpret_cast<const bf16x8*>(kb + 32 + lg * 8);
            f32x4 t = {};
            t = __builtin_amdgcn_mfma_f32_16x16x32_bf16(qf[0], kf0, t, 0, 0, 0);
            t = __builtin_amdgcn_mfma_f32_16x16x32_bf16(qf[1], kf1, t, 0, 0, 0);
            s[ct] = t;
        }
        // online softmax over 64 keys
        float al[4];
        #pragma unroll
        for (int r = 0; r < 4; ++r) {
            float mm = fmaxf(fmaxf(s[0][r], s[1][r]), fmaxf(s[2][r], s[3][r]));
            mm = fmaxf(mm, __shfl_xor(mm, 1));
            mm = fmaxf(mm, __shfl_xor(mm, 2));
            mm = fmaxf(mm, __shfl_xor(mm, 4));
            mm = fmaxf(mm, __shfl_xor(mm, 8));
            float mn = fmaxf(m_run[r], mm);
            al[r] = __expf(m_run[r] - mn);
            m_run[r] = mn;
            float p0 = __expf(s[0][r] - mn);
            float p1 = __expf(s[1][r] - mn);
            float p2 = __expf(s[2][r] - mn);
            float p3 = __expf(s[3][r] - mn);
            s[0][r] = p0; s[1][r] = p1; s[2][r] = p2; s[3][r] = p3;
            float rs = (p0 + p1) + (p2 + p3);
            rs += __shfl_xor(rs, 1);
            rs += __shfl_xor(rs, 2);
            rs += __shfl_xor(rs, 4);
            rs += __shfl_xor(rs, 8);
            l_run[r] = l_run[r] * al[r] + rs;
        }
        #pragma unroll
        for (int dt = 0; dt < 4; ++dt)
            #pragma unroll
            for (int r = 0; r < 4; ++r)
                o_acc[dt][r] *= al[r];
        // P -> LDS (bf16), wave-local
        #pragma unroll
        for (int ct = 0; ct < 4; ++ct)
            #pragma unroll
            for (int r = 0; r < 4; ++r)
                P_lds[w][lg * 4 + r][ct * 16 + lr] = (bf16_t)s[ct][r];
        asm volatile("s_waitcnt lgkmcnt(0)" ::: "memory");
        // O += P V
        #pragma unroll
        for (int kk2 = 0; kk2 < 2; ++kk2) {
            bf16x8 ap = *reinterpret_cast<const bf16x8*>(&P_lds[w][lr][kk2 * 32 + lg * 8]);
            #pragma unroll
            for (int dt = 0; dt < 4; ++dt) {
                bf16x8 vf = *reinterpret_cast<const bf16x8*>(
                    vbase + (size_t)(dt * 16 + lr) * L + kt * 64 + kk2 * 32 + lg * 8);
                o_acc[dt] = __builtin_amdgcn_mfma_f32_16x16x32_bf16(ap, vf, o_acc[dt], 0, 0, 0);
            }
        }
    }
    // epilogue: normalize, write merged-head layout [t][E] fp32
    #pragma unroll
    for (int dt = 0; dt < 4; ++dt)
        #pragma unroll
        for (int r = 0; r < 4; ++r) {
            int qrow = q0 + lg * 4 + r;
            attn_out[(size_t)(nb * L + qrow) * E + head * HD + dt * 16 + lr] = o_acc[dt][r] / l_run[r];
        }
}

// ---------------- launch ----------------
extern "C" void kernel_launch(void* const* d_in, const int* in_sizes, int n_in,
                              void* d_out, int out_size, void* d_ws, size_t ws_size,
                              hipStream_t stream)
{
    const float* query = (const float*)d_in[0];
    const float* key   = (const float*)d_in[1];
    const float* value = (const float*)d_in[2];
    const float* Wq = (const float*)d_in[3];
    const float* bq = (const float*)d_in[4];
    const float* Wk = (const float*)d_in[5];
    const float* bk = (const float*)d_in[6];
    const float* Wv = (const float*)d_in[7];
    const float* bv = (const float*)d_in[8];
    const float* Wo = (const float*)d_in[9];
    const float* bo = (const float*)d_in[10];

    char* ws = (char*)d_ws;
    constexpr size_t QKV_BYTES = (size_t)BH * L * HD * sizeof(bf16_t);  // 9437184
    float*  tabs    = (float*)(ws);
    bf16_t* q_ws    = (bf16_t*)(ws + 16384);
    bf16_t* k_ws    = (bf16_t*)(ws + 16384 + 1 * QKV_BYTES);
    bf16_t* v_ws    = (bf16_t*)(ws + 16384 + 2 * QKV_BYTES);
    bf16_t* vT_ws   = (bf16_t*)(ws + 16384 + 3 * QKV_BYTES);
    float*  attn_ws = (float*) (ws + 16384 + 4 * QKV_BYTES);

    xpos_tables_kernel<<<1, 768, 0, stream>>>(tabs);

    dim3 gg(T / 128, E / 128), gb(256);
    gemm_kernel<0><<<gg, gb, 0, stream>>>(query, Wq, bq, (void*)q_ws);
    gemm_kernel<1><<<gg, gb, 0, stream>>>(key,   Wk, bk, (void*)k_ws);
    gemm_kernel<2><<<gg, gb, 0, stream>>>(value, Wv, bv, (void*)v_ws);

    xpos_apply_kernel<<<(BH * L + 255) / 256, 256, 0, stream>>>(q_ws, k_ws, tabs);
    v_transpose_kernel<<<dim3(L / 64, BH), 256, 0, stream>>>(v_ws, vT_ws);

    attn_kernel<<<dim3(L / 64, BH), 256, 0, stream>>>(q_ws, k_ws, vT_ws, attn_ws);

    gemm_kernel<3><<<gg, gb, 0, stream>>>(attn_ws, Wo, bo, (float*)d_out);
}

// Round 2
// 451.613 us; speedup vs baseline: 1.0433x; 1.0433x over previous
//
#include <hip/hip_runtime.h>
#include <hip/hip_bf16.h>

typedef __bf16 bf16_t;
typedef __bf16 bf16x4 __attribute__((ext_vector_type(4)));
typedef __bf16 bf16x8 __attribute__((ext_vector_type(8)));
typedef float f32x4 __attribute__((ext_vector_type(4)));

constexpr int E  = 1024;
constexpr int NH = 16;
constexpr int HD = 64;
constexpr int NB = 2;
constexpr int GS = 48;          // spatial side
constexpr int L  = GS * GS;     // 2304 tokens per batch
constexpr int T  = NB * L;      // 4608 tokens
constexpr int BH = NB * NH;     // 32 batch*head

static __device__ __forceinline__ f32x4 vmax4(f32x4 a, f32x4 b) {
    f32x4 r;
    r[0] = fmaxf(a[0], b[0]); r[1] = fmaxf(a[1], b[1]);
    r[2] = fmaxf(a[2], b[2]); r[3] = fmaxf(a[3], b[3]);
    return r;
}

// ---------------- xpos tables: [4][48][16] = cs_q, ss_q, cs_k, ss_k ----------------
__global__ void xpos_tables_kernel(float* __restrict__ tabs) {
    int i = threadIdx.x;
    if (i >= GS * 16) return;
    int p = i >> 4, j = i & 15;
    float sv = (2.0f * (float)j + 12.8f) / 44.8f;
    float pw = ((float)p - 24.0f) / 512.0f;
    float scale = powf(sv, pw);
    float inv_freq = powf(10000.0f, -(float)j / 16.0f);
    float ang = (float)p * inv_freq;
    float s = sinf(ang), c = cosf(ang);
    tabs[0 * 768 + i] = c * scale;   // q: downscale=False
    tabs[1 * 768 + i] = s * scale;
    tabs[2 * 768 + i] = c / scale;   // k: downscale=True
    tabs[3 * 768 + i] = s / scale;
}

// ---------------- fused QKV GEMM (z = 0:Q+xpos, 1:K+xpos, 2:V transposed) ----------
__global__ __launch_bounds__(256, 2)
void qkv_gemm_kernel(const float* __restrict__ Aq, const float* __restrict__ Ak,
                     const float* __restrict__ Av,
                     const float* __restrict__ Wq, const float* __restrict__ Wk,
                     const float* __restrict__ Wv,
                     const float* __restrict__ bq, const float* __restrict__ bk,
                     const float* __restrict__ bv,
                     bf16_t* __restrict__ q_ws, bf16_t* __restrict__ k_ws,
                     bf16_t* __restrict__ vT_ws, const float* __restrict__ tabs)
{
    __shared__ bf16_t As[128 * 64];
    __shared__ bf16_t Bs[128 * 64];
    const int z = blockIdx.z;
    const float* A    = (z == 0) ? Aq : (z == 1) ? Ak : Av;
    const float* W    = (z == 0) ? Wq : (z == 1) ? Wk : Wv;
    const float* bias = (z == 0) ? bq : (z == 1) ? bk : bv;

    const int tid = threadIdx.x;
    const int lane = tid & 63;
    const int wv = tid >> 6;
    const int wm = wv >> 1, wn = wv & 1;
    const int lr = lane & 15, lg = lane >> 4;
    const int bm = blockIdx.x, bn = blockIdx.y;

    f32x4 acc[4][4] = {};

    for (int kt = 0; kt < E / 64; ++kt) {
        const int k0 = kt * 64;
        __syncthreads();
        #pragma unroll
        for (int it = 0; it < 4; ++it) {
            int ci = it * 256 + tid;      // 0..1023 : 128 rows x 8 chunks(8 elem)
            int row = ci >> 3, c = ci & 7;
            int sw = ((c ^ (row & 7)) * 8);
            const float* srcA = A + (size_t)(bm * 128 + row) * E + k0 + c * 8;
            f32x4 a0 = *reinterpret_cast<const f32x4*>(srcA);
            f32x4 a1 = *reinterpret_cast<const f32x4*>(srcA + 4);
            bf16x8 ha;
            ha[0] = (bf16_t)a0[0]; ha[1] = (bf16_t)a0[1]; ha[2] = (bf16_t)a0[2]; ha[3] = (bf16_t)a0[3];
            ha[4] = (bf16_t)a1[0]; ha[5] = (bf16_t)a1[1]; ha[6] = (bf16_t)a1[2]; ha[7] = (bf16_t)a1[3];
            *reinterpret_cast<bf16x8*>(&As[row * 64 + sw]) = ha;
            const float* srcB = W + (size_t)(bn * 128 + row) * E + k0 + c * 8;
            f32x4 b0 = *reinterpret_cast<const f32x4*>(srcB);
            f32x4 b1 = *reinterpret_cast<const f32x4*>(srcB + 4);
            bf16x8 hb;
            hb[0] = (bf16_t)b0[0]; hb[1] = (bf16_t)b0[1]; hb[2] = (bf16_t)b0[2]; hb[3] = (bf16_t)b0[3];
            hb[4] = (bf16_t)b1[0]; hb[5] = (bf16_t)b1[1]; hb[6] = (bf16_t)b1[2]; hb[7] = (bf16_t)b1[3];
            *reinterpret_cast<bf16x8*>(&Bs[row * 64 + sw]) = hb;
        }
        __syncthreads();
        #pragma unroll
        for (int kk = 0; kk < 2; ++kk) {
            bf16x8 af[4], bfr[4];
            #pragma unroll
            for (int m = 0; m < 4; ++m) {
                int row = wm * 64 + m * 16 + lr;
                af[m] = *reinterpret_cast<const bf16x8*>(&As[row * 64 + (((kk * 4 + lg) ^ (row & 7)) * 8)]);
            }
            #pragma unroll
            for (int n = 0; n < 4; ++n) {
                int row = wn * 64 + n * 16 + lr;
                bfr[n] = *reinterpret_cast<const bf16x8*>(&Bs[row * 64 + (((kk * 4 + lg) ^ (row & 7)) * 8)]);
            }
            #pragma unroll
            for (int m = 0; m < 4; ++m)
                #pragma unroll
                for (int n = 0; n < 4; ++n)
                    acc[m][n] = __builtin_amdgcn_mfma_f32_16x16x32_bf16(af[m], bfr[n], acc[m][n], 0, 0, 0);
        }
    }

    if (z < 2) {
        // Q/K epilogue: bias, (Q: *0.125), fused xpos rotation, write [bh][l][d] bf16
        const float* cs_t = tabs + (z == 0 ? 0 : 1536);
        const float* ss_t = tabs + (z == 0 ? 768 : 2304);
        bf16_t* dst = (z == 0) ? q_ws : k_ws;
        #pragma unroll
        for (int m = 0; m < 4; ++m) {
            #pragma unroll
            for (int n = 0; n < 4; ++n) {
                const int col = bn * 128 + wn * 64 + n * 16 + lr;
                const float bvv = bias[col];
                const int head = col >> 6, d = col & 63;
                const int j = (d & 31) >> 1, half = d >> 5, odd = d & 1;
                #pragma unroll
                for (int r = 0; r < 4; ++r) {
                    const int rowg = bm * 128 + wm * 64 + m * 16 + lg * 4 + r;
                    const int nb = rowg / L, ll = rowg - nb * L;
                    const int y = ll / GS, x = ll - y * GS;
                    const int pos = half ? y : x;
                    float v = acc[m][n][r] + bvv;
                    if (z == 0) v *= 0.125f;
                    float o = __shfl_xor(v, 1);
                    float cs = cs_t[pos * 16 + j], ss = ss_t[pos * 16 + j];
                    float res = odd ? (v * cs + o * ss) : (v * cs - o * ss);
                    dst[((size_t)(nb * NH + head) * L + ll) * HD + d] = (bf16_t)res;
                }
            }
        }
    } else {
        // V epilogue: bias, write transposed [bh][d][l] bf16 (bf16x4 along l)
        #pragma unroll
        for (int m = 0; m < 4; ++m) {
            const int rowg0 = bm * 128 + wm * 64 + m * 16 + lg * 4;
            const int nb = rowg0 / L, ll0 = rowg0 - nb * L;
            #pragma unroll
            for (int n = 0; n < 4; ++n) {
                const int col = bn * 128 + wn * 64 + n * 16 + lr;
                const float bvv = bias[col];
                const int head = col >> 6, d = col & 63;
                bf16x4 pk;
                #pragma unroll
                for (int r = 0; r < 4; ++r) pk[r] = (bf16_t)(acc[m][n][r] + bvv);
                *reinterpret_cast<bf16x4*>(&vT_ws[((size_t)(nb * NH + head) * HD + d) * L + ll0]) = pk;
            }
        }
    }
}

// ---------------- flash attention: swapped-QK^T, in-lane softmax ----------------
// grid (L/64, BH), 256 threads = 4 independent waves; wave handles 16 queries, KBLK=128.
__global__ __launch_bounds__(256, 3)
void attn_kernel(const bf16_t* __restrict__ q_ws, const bf16_t* __restrict__ k_ws,
                 const bf16_t* __restrict__ vT_ws, bf16_t* __restrict__ attn_out)
{
    __shared__ bf16_t P_lds[4][16][136];   // per-wave [q][key], padded stride
    const int tid = threadIdx.x;
    const int lane = tid & 63, w = tid >> 6;
    const int lr = lane & 15, lg = lane >> 4;
    const int bh = blockIdx.y;
    const int q0 = blockIdx.x * 64 + w * 16;
    const int nb = bh >> 4, head = bh & 15;

    const bf16_t* qb = q_ws + (size_t)bh * L * HD;
    const bf16_t* kb = k_ws + (size_t)bh * L * HD;
    const bf16_t* vb = vT_ws + (size_t)bh * HD * L;

    bf16x8 qf[2];
    qf[0] = *reinterpret_cast<const bf16x8*>(qb + (size_t)(q0 + lr) * HD + lg * 8);
    qf[1] = *reinterpret_cast<const bf16x8*>(qb + (size_t)(q0 + lr) * HD + 32 + lg * 8);

    f32x4 o_acc[4] = {};
    float m_run = -1e30f, l_run = 0.0f;

    for (int kt = 0; kt < L / 128; ++kt) {
        const bf16_t* kbase = kb + (size_t)kt * 128 * HD;
        // S^T = K Q^T : lane holds S[key = ct*16 + lg*4 + r][q = lr]
        f32x4 s[8];
        #pragma unroll
        for (int ct = 0; ct < 8; ++ct) {
            const bf16_t* kr = kbase + (size_t)(ct * 16 + lr) * HD;
            bf16x8 k0 = *reinterpret_cast<const bf16x8*>(kr + lg * 8);
            bf16x8 k1 = *reinterpret_cast<const bf16x8*>(kr + 32 + lg * 8);
            f32x4 t = {};
            t = __builtin_amdgcn_mfma_f32_16x16x32_bf16(k0, qf[0], t, 0, 0, 0);
            t = __builtin_amdgcn_mfma_f32_16x16x32_bf16(k1, qf[1], t, 0, 0, 0);
            s[ct] = t;
        }
        // in-lane max tree over 32 keys, then 2 shfls across lg quads
        f32x4 m01 = vmax4(s[0], s[1]), m23 = vmax4(s[2], s[3]);
        f32x4 m45 = vmax4(s[4], s[5]), m67 = vmax4(s[6], s[7]);
        f32x4 ma = vmax4(vmax4(m01, m23), vmax4(m45, m67));
        float mt = fmaxf(fmaxf(ma[0], ma[1]), fmaxf(ma[2], ma[3]));
        mt = fmaxf(mt, __shfl_xor(mt, 16));
        mt = fmaxf(mt, __shfl_xor(mt, 32));
        const float mn = fmaxf(m_run, mt);
        const float al = __expf(m_run - mn);
        m_run = mn;
        // exp
        #pragma unroll
        for (int ct = 0; ct < 8; ++ct) {
            #pragma unroll
            for (int r = 0; r < 4; ++r) s[ct][r] = __expf(s[ct][r] - mn);
        }
        // in-lane sum tree + 2 shfls
        f32x4 s01 = s[0] + s[1], s23 = s[2] + s[3], s45 = s[4] + s[5], s67 = s[6] + s[7];
        f32x4 sa = (s01 + s23) + (s45 + s67);
        float rs = (sa[0] + sa[1]) + (sa[2] + sa[3]);
        rs += __shfl_xor(rs, 16);
        rs += __shfl_xor(rs, 32);
        l_run = l_run * al + rs;
        // P -> LDS (bf16x4 per ct: 4 consecutive keys for query lr)
        #pragma unroll
        for (int ct = 0; ct < 8; ++ct) {
            bf16x4 p;
            p[0] = (bf16_t)s[ct][0]; p[1] = (bf16_t)s[ct][1];
            p[2] = (bf16_t)s[ct][2]; p[3] = (bf16_t)s[ct][3];
            *reinterpret_cast<bf16x4*>(&P_lds[w][lr][ct * 16 + lg * 4]) = p;
        }
        asm volatile("s_waitcnt lgkmcnt(0)" ::: "memory");
        __builtin_amdgcn_sched_barrier(0);
        // rescale O by al broadcast to row layout
        float alr[4];
        #pragma unroll
        for (int r = 0; r < 4; ++r) alr[r] = __shfl(al, lg * 4 + r);
        #pragma unroll
        for (int dt = 0; dt < 4; ++dt) {
            #pragma unroll
            for (int r = 0; r < 4; ++r) o_acc[dt][r] *= alr[r];
        }
        // O += P V
        const bf16_t* vbase = vb + (size_t)kt * 128;
        #pragma unroll
        for (int kk2 = 0; kk2 < 4; ++kk2) {
            bf16x8 ap = *reinterpret_cast<const bf16x8*>(&P_lds[w][lr][kk2 * 32 + lg * 8]);
            #pragma unroll
            for (int dt = 0; dt < 4; ++dt) {
                bf16x8 vf = *reinterpret_cast<const bf16x8*>(
                    vbase + (size_t)(dt * 16 + lr) * L + kk2 * 32 + lg * 8);
                o_acc[dt] = __builtin_amdgcn_mfma_f32_16x16x32_bf16(ap, vf, o_acc[dt], 0, 0, 0);
            }
        }
    }
    // epilogue: normalize, write merged-head layout [t][E] bf16
    float invl[4];
    #pragma unroll
    for (int r = 0; r < 4; ++r) invl[r] = 1.0f / __shfl(l_run, lg * 4 + r);
    #pragma unroll
    for (int dt = 0; dt < 4; ++dt) {
        #pragma unroll
        for (int r = 0; r < 4; ++r) {
            int qrow = q0 + lg * 4 + r;
            attn_out[(size_t)(nb * L + qrow) * E + head * HD + dt * 16 + lr] =
                (bf16_t)(o_acc[dt][r] * invl[r]);
        }
    }
}

// ---------------- output projection GEMM (A bf16) ----------------
__global__ __launch_bounds__(256, 2)
void out_gemm_kernel(const bf16_t* __restrict__ A, const float* __restrict__ W,
                     const float* __restrict__ bias, float* __restrict__ outp)
{
    __shared__ bf16_t As[128 * 64];
    __shared__ bf16_t Bs[128 * 64];
    const int tid = threadIdx.x;
    const int lane = tid & 63;
    const int wv = tid >> 6;
    const int wm = wv >> 1, wn = wv & 1;
    const int lr = lane & 15, lg = lane >> 4;
    const int bm = blockIdx.x, bn = blockIdx.y;

    f32x4 acc[4][4] = {};

    for (int kt = 0; kt < E / 64; ++kt) {
        const int k0 = kt * 64;
        __syncthreads();
        #pragma unroll
        for (int it = 0; it < 4; ++it) {
            int ci = it * 256 + tid;
            int row = ci >> 3, c = ci & 7;
            int sw = ((c ^ (row & 7)) * 8);
            bf16x8 ha = *reinterpret_cast<const bf16x8*>(A + (size_t)(bm * 128 + row) * E + k0 + c * 8);
            *reinterpret_cast<bf16x8*>(&As[row * 64 + sw]) = ha;
            const float* srcB = W + (size_t)(bn * 128 + row) * E + k0 + c * 8;
            f32x4 b0 = *reinterpret_cast<const f32x4*>(srcB);
            f32x4 b1 = *reinterpret_cast<const f32x4*>(srcB + 4);
            bf16x8 hb;
            hb[0] = (bf16_t)b0[0]; hb[1] = (bf16_t)b0[1]; hb[2] = (bf16_t)b0[2]; hb[3] = (bf16_t)b0[3];
            hb[4] = (bf16_t)b1[0]; hb[5] = (bf16_t)b1[1]; hb[6] = (bf16_t)b1[2]; hb[7] = (bf16_t)b1[3];
            *reinterpret_cast<bf16x8*>(&Bs[row * 64 + sw]) = hb;
        }
        __syncthreads();
        #pragma unroll
        for (int kk = 0; kk < 2; ++kk) {
            bf16x8 af[4], bfr[4];
            #pragma unroll
            for (int m = 0; m < 4; ++m) {
                int row = wm * 64 + m * 16 + lr;
                af[m] = *reinterpret_cast<const bf16x8*>(&As[row * 64 + (((kk * 4 + lg) ^ (row & 7)) * 8)]);
            }
            #pragma unroll
            for (int n = 0; n < 4; ++n) {
                int row = wn * 64 + n * 16 + lr;
                bfr[n] = *reinterpret_cast<const bf16x8*>(&Bs[row * 64 + (((kk * 4 + lg) ^ (row & 7)) * 8)]);
            }
            #pragma unroll
            for (int m = 0; m < 4; ++m)
                #pragma unroll
                for (int n = 0; n < 4; ++n)
                    acc[m][n] = __builtin_amdgcn_mfma_f32_16x16x32_bf16(af[m], bfr[n], acc[m][n], 0, 0, 0);
        }
    }

    #pragma unroll
    for (int m = 0; m < 4; ++m) {
        #pragma unroll
        for (int n = 0; n < 4; ++n) {
            const int col = bn * 128 + wn * 64 + n * 16 + lr;
            const float bvv = bias[col];
            #pragma unroll
            for (int r = 0; r < 4; ++r) {
                const int rowg = bm * 128 + wm * 64 + m * 16 + lg * 4 + r;
                outp[(size_t)rowg * E + col] = acc[m][n][r] + bvv;
            }
        }
    }
}

// ---------------- launch ----------------
extern "C" void kernel_launch(void* const* d_in, const int* in_sizes, int n_in,
                              void* d_out, int out_size, void* d_ws, size_t ws_size,
                              hipStream_t stream)
{
    const float* query = (const float*)d_in[0];
    const float* key   = (const float*)d_in[1];
    const float* value = (const float*)d_in[2];
    const float* Wq = (const float*)d_in[3];
    const float* bq = (const float*)d_in[4];
    const float* Wk = (const float*)d_in[5];
    const float* bk = (const float*)d_in[6];
    const float* Wv = (const float*)d_in[7];
    const float* bv = (const float*)d_in[8];
    const float* Wo = (const float*)d_in[9];
    const float* bo = (const float*)d_in[10];

    char* ws = (char*)d_ws;
    constexpr size_t QKV_BYTES = (size_t)BH * L * HD * sizeof(bf16_t);  // 9437184
    float*  tabs    = (float*)(ws);
    bf16_t* q_ws    = (bf16_t*)(ws + 16384);
    bf16_t* k_ws    = (bf16_t*)(ws + 16384 + 1 * QKV_BYTES);
    bf16_t* vT_ws   = (bf16_t*)(ws + 16384 + 2 * QKV_BYTES);
    bf16_t* attn_ws = (bf16_t*)(ws + 16384 + 3 * QKV_BYTES);

    xpos_tables_kernel<<<1, 768, 0, stream>>>(tabs);

    qkv_gemm_kernel<<<dim3(T / 128, E / 128, 3), 256, 0, stream>>>(
        query, key, value, Wq, Wk, Wv, bq, bk, bv, q_ws, k_ws, vT_ws, tabs);

    attn_kernel<<<dim3(L / 64, BH), 256, 0, stream>>>(q_ws, k_ws, vT_ws, attn_ws);

    out_gemm_kernel<<<dim3(T / 128, E / 128), 256, 0, stream>>>(attn_ws, Wo, bo, (float*)d_out);
}

// Round 4
// 246.364 us; speedup vs baseline: 1.9124x; 1.8331x over previous
//
#include <hip/hip_runtime.h>
#include <hip/hip_bf16.h>

typedef __bf16 bf16_t;
typedef __bf16 bf16x4 __attribute__((ext_vector_type(4)));
typedef __bf16 bf16x8 __attribute__((ext_vector_type(8)));
typedef float f32x4 __attribute__((ext_vector_type(4)));
typedef unsigned long long ull;

constexpr int E  = 1024;
constexpr int NH = 16;
constexpr int HD = 64;
constexpr int NB = 2;
constexpr int GS = 48;          // spatial side
constexpr int L  = GS * GS;     // 2304 tokens per batch
constexpr int T  = NB * L;      // 4608 tokens
constexpr int BH = NB * NH;     // 32 batch*head

static __device__ __forceinline__ f32x4 vmax4(f32x4 a, f32x4 b) {
    f32x4 r;
    r[0] = fmaxf(a[0], b[0]); r[1] = fmaxf(a[1], b[1]);
    r[2] = fmaxf(a[2], b[2]); r[3] = fmaxf(a[3], b[3]);
    return r;
}

static __device__ __forceinline__ void gload16(const void* g, void* l) {
    __builtin_amdgcn_global_load_lds(
        (const __attribute__((address_space(1))) unsigned int*)g,
        (__attribute__((address_space(3))) unsigned int*)l, 16, 0, 0);
}

// ---------------- xpos tables: [4][48][16] = cs_q, ss_q, cs_k, ss_k ----------------
__global__ void xpos_tables_kernel(float* __restrict__ tabs) {
    int i = threadIdx.x;
    if (i >= GS * 16) return;
    int p = i >> 4, j = i & 15;
    float sv = (2.0f * (float)j + 12.8f) / 44.8f;
    float pw = ((float)p - 24.0f) / 512.0f;
    float scale = powf(sv, pw);
    float inv_freq = powf(10000.0f, -(float)j / 16.0f);
    float ang = (float)p * inv_freq;
    float s = sinf(ang), c = cosf(ang);
    tabs[0 * 768 + i] = c * scale;   // q: downscale=False
    tabs[1 * 768 + i] = s * scale;
    tabs[2 * 768 + i] = c / scale;   // k: downscale=True
    tabs[3 * 768 + i] = s / scale;
}

// ---------------- fused QKV GEMM (z = 0:Q+xpos, 1:K+xpos, 2:V transposed) ----------
__global__ __launch_bounds__(256, 2)
void qkv_gemm_kernel(const float* __restrict__ Aq, const float* __restrict__ Ak,
                     const float* __restrict__ Av,
                     const float* __restrict__ Wq, const float* __restrict__ Wk,
                     const float* __restrict__ Wv,
                     const float* __restrict__ bq, const float* __restrict__ bk,
                     const float* __restrict__ bv,
                     bf16_t* __restrict__ q_ws, bf16_t* __restrict__ k_ws,
                     bf16_t* __restrict__ vT_ws, const float* __restrict__ tabs)
{
    __shared__ bf16_t As[128 * 64];
    __shared__ bf16_t Bs[128 * 64];
    const int z = blockIdx.z;
    const float* A    = (z == 0) ? Aq : (z == 1) ? Ak : Av;
    const float* W    = (z == 0) ? Wq : (z == 1) ? Wk : Wv;
    const float* bias = (z == 0) ? bq : (z == 1) ? bk : bv;

    const int tid = threadIdx.x;
    const int lane = tid & 63;
    const int wv = tid >> 6;
    const int wm = wv >> 1, wn = wv & 1;
    const int lr = lane & 15, lg = lane >> 4;
    const int bm = blockIdx.x, bn = blockIdx.y;

    f32x4 acc[4][4] = {};

    for (int kt = 0; kt < E / 64; ++kt) {
        const int k0 = kt * 64;
        __syncthreads();
        #pragma unroll
        for (int it = 0; it < 4; ++it) {
            int ci = it * 256 + tid;      // 0..1023 : 128 rows x 8 chunks(8 elem)
            int row = ci >> 3, c = ci & 7;
            int sw = ((c ^ (row & 7)) * 8);
            const float* srcA = A + (size_t)(bm * 128 + row) * E + k0 + c * 8;
            f32x4 a0 = *reinterpret_cast<const f32x4*>(srcA);
            f32x4 a1 = *reinterpret_cast<const f32x4*>(srcA + 4);
            bf16x8 ha;
            ha[0] = (bf16_t)a0[0]; ha[1] = (bf16_t)a0[1]; ha[2] = (bf16_t)a0[2]; ha[3] = (bf16_t)a0[3];
            ha[4] = (bf16_t)a1[0]; ha[5] = (bf16_t)a1[1]; ha[6] = (bf16_t)a1[2]; ha[7] = (bf16_t)a1[3];
            *reinterpret_cast<bf16x8*>(&As[row * 64 + sw]) = ha;
            const float* srcB = W + (size_t)(bn * 128 + row) * E + k0 + c * 8;
            f32x4 b0 = *reinterpret_cast<const f32x4*>(srcB);
            f32x4 b1 = *reinterpret_cast<const f32x4*>(srcB + 4);
            bf16x8 hb;
            hb[0] = (bf16_t)b0[0]; hb[1] = (bf16_t)b0[1]; hb[2] = (bf16_t)b0[2]; hb[3] = (bf16_t)b0[3];
            hb[4] = (bf16_t)b1[0]; hb[5] = (bf16_t)b1[1]; hb[6] = (bf16_t)b1[2]; hb[7] = (bf16_t)b1[3];
            *reinterpret_cast<bf16x8*>(&Bs[row * 64 + sw]) = hb;
        }
        __syncthreads();
        #pragma unroll
        for (int kk = 0; kk < 2; ++kk) {
            bf16x8 af[4], bfr[4];
            #pragma unroll
            for (int m = 0; m < 4; ++m) {
                int row = wm * 64 + m * 16 + lr;
                af[m] = *reinterpret_cast<const bf16x8*>(&As[row * 64 + (((kk * 4 + lg) ^ (row & 7)) * 8)]);
            }
            #pragma unroll
            for (int n = 0; n < 4; ++n) {
                int row = wn * 64 + n * 16 + lr;
                bfr[n] = *reinterpret_cast<const bf16x8*>(&Bs[row * 64 + (((kk * 4 + lg) ^ (row & 7)) * 8)]);
            }
            #pragma unroll
            for (int m = 0; m < 4; ++m)
                #pragma unroll
                for (int n = 0; n < 4; ++n)
                    acc[m][n] = __builtin_amdgcn_mfma_f32_16x16x32_bf16(af[m], bfr[n], acc[m][n], 0, 0, 0);
        }
    }

    if (z < 2) {
        const float* cs_t = tabs + (z == 0 ? 0 : 1536);
        const float* ss_t = tabs + (z == 0 ? 768 : 2304);
        bf16_t* dst = (z == 0) ? q_ws : k_ws;
        #pragma unroll
        for (int m = 0; m < 4; ++m) {
            #pragma unroll
            for (int n = 0; n < 4; ++n) {
                const int col = bn * 128 + wn * 64 + n * 16 + lr;
                const float bvv = bias[col];
                const int head = col >> 6, d = col & 63;
                const int j = (d & 31) >> 1, half = d >> 5, odd = d & 1;
                #pragma unroll
                for (int r = 0; r < 4; ++r) {
                    const int rowg = bm * 128 + wm * 64 + m * 16 + lg * 4 + r;
                    const int nb = rowg / L, ll = rowg - nb * L;
                    const int y = ll / GS, x = ll - y * GS;
                    const int pos = half ? y : x;
                    float v = acc[m][n][r] + bvv;
                    if (z == 0) v *= 0.125f;
                    float o = __shfl_xor(v, 1);
                    float cs = cs_t[pos * 16 + j], ss = ss_t[pos * 16 + j];
                    float res = odd ? (v * cs + o * ss) : (v * cs - o * ss);
                    dst[((size_t)(nb * NH + head) * L + ll) * HD + d] = (bf16_t)res;
                }
            }
        }
    } else {
        #pragma unroll
        for (int m = 0; m < 4; ++m) {
            const int rowg0 = bm * 128 + wm * 64 + m * 16 + lg * 4;
            const int nb = rowg0 / L, ll0 = rowg0 - nb * L;
            #pragma unroll
            for (int n = 0; n < 4; ++n) {
                const int col = bn * 128 + wn * 64 + n * 16 + lr;
                const float bvv = bias[col];
                const int head = col >> 6, d = col & 63;
                bf16x4 pk;
                #pragma unroll
                for (int r = 0; r < 4; ++r) pk[r] = (bf16_t)(acc[m][n][r] + bvv);
                *reinterpret_cast<bf16x4*>(&vT_ws[((size_t)(nb * NH + head) * HD + d) * L + ll0]) = pk;
            }
        }
    }
}

// ---------------- flash attention: LDS-staged double-buffered K/V, O^T PV ----------
// grid (L/64, BH), 256 threads = 4 waves; wave owns 16 queries; KVBLK = 64.
__global__ __launch_bounds__(256, 4)
void attn_kernel(const bf16_t* __restrict__ q_ws, const bf16_t* __restrict__ k_ws,
                 const bf16_t* __restrict__ vT_ws, bf16_t* __restrict__ attn_out)
{
    __shared__ bf16_t K_lds[2][64 * 64];   // [l][d], chunk-XOR-swizzled rows (128B)
    __shared__ bf16_t V_lds[2][64 * 64];   // [d][l], chunk-XOR-swizzled rows (128B)
    const int tid = threadIdx.x;
    const int lane = tid & 63, w = tid >> 6;
    const int lr = lane & 15, lg = lane >> 4;
    const int bh = blockIdx.y;
    const int q0 = blockIdx.x * 64 + w * 16;
    const int nb = bh >> 4, head = bh & 15;

    const bf16_t* qb = q_ws + (size_t)bh * L * HD;
    const bf16_t* kb = k_ws + (size_t)bh * L * HD;
    const bf16_t* vb = vT_ws + (size_t)bh * HD * L;

    // staging: wave w covers LDS bytes [w*2048, w*2048+2048) of each 8KB tile,
    // two 1024B issues. slot s = w*128 + it*64 + lane; r = s>>3, c = s&7.
    // LDS[r][c] holds global chunk c^(r&7)  (inverse-swizzled source, m173).
    const int s0 = w * 128 + lane;           // it=0
    const int r0 = s0 >> 3, c0 = s0 & 7;
    const int cx = c0 ^ (r0 & 7);
    const bf16_t* kst = kb + r0 * HD + cx * 8;           // advance 4096 elems per tile
    const bf16_t* vst = vb + (size_t)r0 * L + cx * 8;    // advance 64 elems per tile

    bf16x8 qf[2];
    qf[0] = *reinterpret_cast<const bf16x8*>(qb + (size_t)(q0 + lr) * HD + lg * 8);
    qf[1] = *reinterpret_cast<const bf16x8*>(qb + (size_t)(q0 + lr) * HD + 32 + lg * 8);

    f32x4 o_acc[4] = {};
    float m_run = -1e30f, l_run = 0.0f;

    // prologue: stage tile 0 into buffer 0
    gload16(kst,           &K_lds[0][w * 1024]);
    gload16(kst + 512,     &K_lds[0][w * 1024 + 512]);
    gload16(vst,           &V_lds[0][w * 1024]);
    gload16(vst + 8 * L,   &V_lds[0][w * 1024 + 512]);
    __syncthreads();

    int cur = 0;
    constexpr int NT = L / 64;   // 36
    for (int kt = 0; kt < NT; ++kt) {
        if (kt + 1 < NT) {
            const bf16_t* kn = kst + (size_t)(kt + 1) * 4096;
            const bf16_t* vn = vst + (kt + 1) * 64;
            bf16_t* kd = &K_lds[cur ^ 1][w * 1024];
            bf16_t* vd = &V_lds[cur ^ 1][w * 1024];
            gload16(kn,         kd);
            gload16(kn + 512,   kd + 512);
            gload16(vn,         vd);
            gload16(vn + 8 * L, vd + 512);
        }
        // S^T = K Q^T : lane holds S[key = ct*16 + lg*4 + r][q = lr]
        f32x4 s[4];
        __builtin_amdgcn_s_setprio(1);
        #pragma unroll
        for (int ct = 0; ct < 4; ++ct) {
            const int row = ct * 16 + lr;
            bf16x8 kf0 = *reinterpret_cast<const bf16x8*>(&K_lds[cur][row * 64 + ((lg ^ (lr & 7)) * 8)]);
            bf16x8 kf1 = *reinterpret_cast<const bf16x8*>(&K_lds[cur][row * 64 + (((4 + lg) ^ (lr & 7)) * 8)]);
            f32x4 t = {};
            t = __builtin_amdgcn_mfma_f32_16x16x32_bf16(kf0, qf[0], t, 0, 0, 0);
            t = __builtin_amdgcn_mfma_f32_16x16x32_bf16(kf1, qf[1], t, 0, 0, 0);
            s[ct] = t;
        }
        __builtin_amdgcn_s_setprio(0);
        // online softmax: 16 in-lane values + 2 shfls across lg
        f32x4 ma = vmax4(vmax4(s[0], s[1]), vmax4(s[2], s[3]));
        float mt = fmaxf(fmaxf(ma[0], ma[1]), fmaxf(ma[2], ma[3]));
        mt = fmaxf(mt, __shfl_xor(mt, 16));
        mt = fmaxf(mt, __shfl_xor(mt, 32));
        const float mn = fmaxf(m_run, mt);
        const float al = __expf(m_run - mn);
        m_run = mn;
        #pragma unroll
        for (int ct = 0; ct < 4; ++ct) {
            #pragma unroll
            for (int r = 0; r < 4; ++r) s[ct][r] = __expf(s[ct][r] - mn);
        }
        f32x4 sa = (s[0] + s[1]) + (s[2] + s[3]);
        float rs = (sa[0] + sa[1]) + (sa[2] + sa[3]);
        rs += __shfl_xor(rs, 16);
        rs += __shfl_xor(rs, 32);
        l_run = l_run * al + rs;
        // pack P rows to bf16 quads: lane (lr,lg) owns key-quad ct*4+lg in pk[ct] (q=lr)
        ull pk[4];
        #pragma unroll
        for (int ct = 0; ct < 4; ++ct) {
            bf16x4 t4;
            t4[0] = (bf16_t)s[ct][0]; t4[1] = (bf16_t)s[ct][1];
            t4[2] = (bf16_t)s[ct][2]; t4[3] = (bf16_t)s[ct][3];
            pk[ct] = *reinterpret_cast<ull*>(&t4);
        }
        // rescale O^T (al is per-q = per-lane)
        #pragma unroll
        for (int dt = 0; dt < 4; ++dt) o_acc[dt] *= al;
        // O^T += V^T P : build P B-frags by cross-lane quad gather.
        // dest (lr,lg), frag kk needs quads t1=kk*8+lg*2 (lo) and t1+1 (hi):
        //   register index ct = kk*2 + (lg>>1), owner lanes (lg&1)*32+lr and +16.
        // __shfl evaluates its value arg in the SOURCE lane -> shuffle both
        // candidate registers (uniform index) and select by dest's lg.
        __builtin_amdgcn_s_setprio(1);
        #pragma unroll
        for (int kk = 0; kk < 2; ++kk) {
            const int bsl = ((lg & 1) << 5) + lr;
            ull a0 = __shfl(pk[kk * 2],     bsl);
            ull a1 = __shfl(pk[kk * 2 + 1], bsl);
            ull b0 = __shfl(pk[kk * 2],     bsl + 16);
            ull b1 = __shfl(pk[kk * 2 + 1], bsl + 16);
            ull lo = (lg & 2) ? a1 : a0;
            ull hi = (lg & 2) ? b1 : b0;
            bf16x8 pa;
            reinterpret_cast<ull*>(&pa)[0] = lo;
            reinterpret_cast<ull*>(&pa)[1] = hi;
            #pragma unroll
            for (int dt = 0; dt < 4; ++dt) {
                const int row = dt * 16 + lr;
                bf16x8 vf = *reinterpret_cast<const bf16x8*>(
                    &V_lds[cur][row * 64 + (((kk * 4 + lg) ^ (lr & 7)) * 8)]);
                o_acc[dt] = __builtin_amdgcn_mfma_f32_16x16x32_bf16(vf, pa, o_acc[dt], 0, 0, 0);
            }
        }
        __builtin_amdgcn_s_setprio(0);
        __syncthreads();   // drains vmcnt (stage) + lgkm; flips buffers safely
        cur ^= 1;
    }

    // epilogue: lane holds O[q=lr][d = dt*16 + lg*4 + r]
    const float inv = 1.0f / l_run;
    #pragma unroll
    for (int dt = 0; dt < 4; ++dt) {
        bf16x4 o;
        #pragma unroll
        for (int r = 0; r < 4; ++r) o[r] = (bf16_t)(o_acc[dt][r] * inv);
        *reinterpret_cast<bf16x4*>(
            &attn_out[(size_t)(nb * L + q0 + lr) * E + head * HD + dt * 16 + lg * 4]) = o;
    }
}

// ---------------- output projection GEMM (A bf16) ----------------
__global__ __launch_bounds__(256, 2)
void out_gemm_kernel(const bf16_t* __restrict__ A, const float* __restrict__ W,
                     const float* __restrict__ bias, float* __restrict__ outp)
{
    __shared__ bf16_t As[128 * 64];
    __shared__ bf16_t Bs[128 * 64];
    const int tid = threadIdx.x;
    const int lane = tid & 63;
    const int wv = tid >> 6;
    const int wm = wv >> 1, wn = wv & 1;
    const int lr = lane & 15, lg = lane >> 4;
    const int bm = blockIdx.x, bn = blockIdx.y;

    f32x4 acc[4][4] = {};

    for (int kt = 0; kt < E / 64; ++kt) {
        const int k0 = kt * 64;
        __syncthreads();
        #pragma unroll
        for (int it = 0; it < 4; ++it) {
            int ci = it * 256 + tid;
            int row = ci >> 3, c = ci & 7;
            int sw = ((c ^ (row & 7)) * 8);
            bf16x8 ha = *reinterpret_cast<const bf16x8*>(A + (size_t)(bm * 128 + row) * E + k0 + c * 8);
            *reinterpret_cast<bf16x8*>(&As[row * 64 + sw]) = ha;
            const float* srcB = W + (size_t)(bn * 128 + row) * E + k0 + c * 8;
            f32x4 b0 = *reinterpret_cast<const f32x4*>(srcB);
            f32x4 b1 = *reinterpret_cast<const f32x4*>(srcB + 4);
            bf16x8 hb;
            hb[0] = (bf16_t)b0[0]; hb[1] = (bf16_t)b0[1]; hb[2] = (bf16_t)b0[2]; hb[3] = (bf16_t)b0[3];
            hb[4] = (bf16_t)b1[0]; hb[5] = (bf16_t)b1[1]; hb[6] = (bf16_t)b1[2]; hb[7] = (bf16_t)b1[3];
            *reinterpret_cast<bf16x8*>(&Bs[row * 64 + sw]) = hb;
        }
        __syncthreads();
        #pragma unroll
        for (int kk = 0; kk < 2; ++kk) {
            bf16x8 af[4], bfr[4];
            #pragma unroll
            for (int m = 0; m < 4; ++m) {
                int row = wm * 64 + m * 16 + lr;
                af[m] = *reinterpret_cast<const bf16x8*>(&As[row * 64 + (((kk * 4 + lg) ^ (row & 7)) * 8)]);
            }
            #pragma unroll
            for (int n = 0; n < 4; ++n) {
                int row = wn * 64 + n * 16 + lr;
                bfr[n] = *reinterpret_cast<const bf16x8*>(&Bs[row * 64 + (((kk * 4 + lg) ^ (row & 7)) * 8)]);
            }
            #pragma unroll
            for (int m = 0; m < 4; ++m)
                #pragma unroll
                for (int n = 0; n < 4; ++n)
                    acc[m][n] = __builtin_amdgcn_mfma_f32_16x16x32_bf16(af[m], bfr[n], acc[m][n], 0, 0, 0);
        }
    }

    #pragma unroll
    for (int m = 0; m < 4; ++m) {
        #pragma unroll
        for (int n = 0; n < 4; ++n) {
            const int col = bn * 128 + wn * 64 + n * 16 + lr;
            const float bvv = bias[col];
            #pragma unroll
            for (int r = 0; r < 4; ++r) {
                const int rowg = bm * 128 + wm * 64 + m * 16 + lg * 4 + r;
                outp[(size_t)rowg * E + col] = acc[m][n][r] + bvv;
            }
        }
    }
}

// ---------------- launch ----------------
extern "C" void kernel_launch(void* const* d_in, const int* in_sizes, int n_in,
                              void* d_out, int out_size, void* d_ws, size_t ws_size,
                              hipStream_t stream)
{
    const float* query = (const float*)d_in[0];
    const float* key   = (const float*)d_in[1];
    const float* value = (const float*)d_in[2];
    const float* Wq = (const float*)d_in[3];
    const float* bq = (const float*)d_in[4];
    const float* Wk = (const float*)d_in[5];
    const float* bk = (const float*)d_in[6];
    const float* Wv = (const float*)d_in[7];
    const float* bv = (const float*)d_in[8];
    const float* Wo = (const float*)d_in[9];
    const float* bo = (const float*)d_in[10];

    char* ws = (char*)d_ws;
    constexpr size_t QKV_BYTES = (size_t)BH * L * HD * sizeof(bf16_t);  // 9437184
    float*  tabs    = (float*)(ws);
    bf16_t* q_ws    = (bf16_t*)(ws + 16384);
    bf16_t* k_ws    = (bf16_t*)(ws + 16384 + 1 * QKV_BYTES);
    bf16_t* vT_ws   = (bf16_t*)(ws + 16384 + 2 * QKV_BYTES);
    bf16_t* attn_ws = (bf16_t*)(ws + 16384 + 3 * QKV_BYTES);

    xpos_tables_kernel<<<1, 768, 0, stream>>>(tabs);

    qkv_gemm_kernel<<<dim3(T / 128, E / 128, 3), 256, 0, stream>>>(
        query, key, value, Wq, Wk, Wv, bq, bk, bv, q_ws, k_ws, vT_ws, tabs);

    attn_kernel<<<dim3(L / 64, BH), 256, 0, stream>>>(q_ws, k_ws, vT_ws, attn_ws);

    out_gemm_kernel<<<dim3(T / 128, E / 128), 256, 0, stream>>>(attn_ws, Wo, bo, (float*)d_out);
}

// Round 5
// 189.370 us; speedup vs baseline: 2.4880x; 1.3010x over previous
//
#include <hip/hip_runtime.h>
#include <hip/hip_bf16.h>

typedef __bf16 bf16_t;
typedef __bf16 bf16x4 __attribute__((ext_vector_type(4)));
typedef __bf16 bf16x8 __attribute__((ext_vector_type(8)));
typedef float f32x4 __attribute__((ext_vector_type(4)));
typedef unsigned long long ull;

constexpr int E  = 1024;
constexpr int NH = 16;
constexpr int HD = 64;
constexpr int NB = 2;
constexpr int GS = 48;          // spatial side
constexpr int L  = GS * GS;     // 2304 tokens per batch
constexpr int T  = NB * L;      // 4608 tokens
constexpr int BH = NB * NH;     // 32 batch*head

static __device__ __forceinline__ f32x4 vmax4(f32x4 a, f32x4 b) {
    f32x4 r;
    r[0] = fmaxf(a[0], b[0]); r[1] = fmaxf(a[1], b[1]);
    r[2] = fmaxf(a[2], b[2]); r[3] = fmaxf(a[3], b[3]);
    return r;
}

static __device__ __forceinline__ void gload16(const void* g, void* l) {
    __builtin_amdgcn_global_load_lds(
        (const __attribute__((address_space(1))) unsigned int*)g,
        (__attribute__((address_space(3))) unsigned int*)l, 16, 0, 0);
}

// ------- prep: cast Wq/Wk/Wv/Wo to bf16 (+ xpos tables in block 0) -------------
// grid 1024 x 256 : thread gid handles f32x4 quad gid of each W (E*E/4 = 262144).
__global__ __launch_bounds__(256)
void prep_kernel(const float* __restrict__ Wq, const float* __restrict__ Wk,
                 const float* __restrict__ Wv, const float* __restrict__ Wo,
                 bf16_t* __restrict__ Wq_b, bf16_t* __restrict__ Wk_b,
                 bf16_t* __restrict__ Wv_b, bf16_t* __restrict__ Wo_b,
                 float* __restrict__ tabs)
{
    if (blockIdx.x == 0) {
        #pragma unroll
        for (int j = 0; j < 3; ++j) {
            int i = threadIdx.x + 256 * j;           // 0..767
            int p = i >> 4, jj = i & 15;
            float sv = (2.0f * (float)jj + 12.8f) / 44.8f;
            float pw = ((float)p - 24.0f) / 512.0f;
            float scale = powf(sv, pw);
            float inv_freq = powf(10000.0f, -(float)jj / 16.0f);
            float ang = (float)p * inv_freq;
            float s = sinf(ang), c = cosf(ang);
            tabs[0 * 768 + i] = c * scale;   // q: downscale=False
            tabs[1 * 768 + i] = s * scale;
            tabs[2 * 768 + i] = c / scale;   // k: downscale=True
            tabs[3 * 768 + i] = s / scale;
        }
    }
    const int gid = blockIdx.x * 256 + threadIdx.x;
    const float* srcs[4] = {Wq, Wk, Wv, Wo};
    bf16_t* dsts[4] = {Wq_b, Wk_b, Wv_b, Wo_b};
    #pragma unroll
    for (int wsel = 0; wsel < 4; ++wsel) {
        f32x4 v = *reinterpret_cast<const f32x4*>(srcs[wsel] + (size_t)gid * 4);
        bf16x4 o;
        o[0] = (bf16_t)v[0]; o[1] = (bf16_t)v[1]; o[2] = (bf16_t)v[2]; o[3] = (bf16_t)v[3];
        *reinterpret_cast<bf16x4*>(dsts[wsel] + (size_t)gid * 4) = o;
    }
}

// ---------------- fused QKV GEMM (z = 0:Q+xpos, 1:K+xpos, 2:V transposed) ----------
// A-side: fp32 sync staging (+cvt). B-side: bf16 W via async global_load_lds.
__global__ __launch_bounds__(256, 3)
void qkv_gemm_kernel(const float* __restrict__ Aq, const float* __restrict__ Ak,
                     const float* __restrict__ Av,
                     const bf16_t* __restrict__ Wqb, const bf16_t* __restrict__ Wkb,
                     const bf16_t* __restrict__ Wvb,
                     const float* __restrict__ bq, const float* __restrict__ bk,
                     const float* __restrict__ bv,
                     bf16_t* __restrict__ q_ws, bf16_t* __restrict__ k_ws,
                     bf16_t* __restrict__ vT_ws, const float* __restrict__ tabs)
{
    __shared__ bf16_t As[128 * 64];
    __shared__ bf16_t Bs[128 * 64];
    const int z = blockIdx.z;
    const float*  A    = (z == 0) ? Aq  : (z == 1) ? Ak  : Av;
    const bf16_t* Wb   = (z == 0) ? Wqb : (z == 1) ? Wkb : Wvb;
    const float*  bias = (z == 0) ? bq  : (z == 1) ? bk  : bv;

    const int tid = threadIdx.x;
    const int lane = tid & 63;
    const int wv = tid >> 6;
    const int wm = wv >> 1, wn = wv & 1;
    const int lr = lane & 15, lg = lane >> 4;
    const int bm = blockIdx.x, bn = blockIdx.y;

    f32x4 acc[4][4] = {};

    for (int kt = 0; kt < E / 64; ++kt) {
        const int k0 = kt * 64;
        __syncthreads();
        // B-side: async bf16 staging, inverse-swizzled source, linear LDS dest
        const bf16_t* Wbase = Wb + (size_t)(bn * 128) * E + k0;
        #pragma unroll
        for (int it = 0; it < 4; ++it) {
            int s = it * 256 + tid;
            int r = s >> 3, c = s & 7;
            gload16(Wbase + (size_t)r * E + ((c ^ (r & 7)) * 8),
                    (char*)Bs + it * 4096 + wv * 1024);
        }
        // A-side: fp32 sync staging + cvt, swizzled ds_write
        #pragma unroll
        for (int it = 0; it < 4; ++it) {
            int ci = it * 256 + tid;
            int row = ci >> 3, c = ci & 7;
            int sw = ((c ^ (row & 7)) * 8);
            const float* srcA = A + (size_t)(bm * 128 + row) * E + k0 + c * 8;
            f32x4 a0 = *reinterpret_cast<const f32x4*>(srcA);
            f32x4 a1 = *reinterpret_cast<const f32x4*>(srcA + 4);
            bf16x8 ha;
            ha[0] = (bf16_t)a0[0]; ha[1] = (bf16_t)a0[1]; ha[2] = (bf16_t)a0[2]; ha[3] = (bf16_t)a0[3];
            ha[4] = (bf16_t)a1[0]; ha[5] = (bf16_t)a1[1]; ha[6] = (bf16_t)a1[2]; ha[7] = (bf16_t)a1[3];
            *reinterpret_cast<bf16x8*>(&As[row * 64 + sw]) = ha;
        }
        __syncthreads();
        #pragma unroll
        for (int kk = 0; kk < 2; ++kk) {
            bf16x8 af[4], bfr[4];
            #pragma unroll
            for (int m = 0; m < 4; ++m) {
                int row = wm * 64 + m * 16 + lr;
                af[m] = *reinterpret_cast<const bf16x8*>(&As[row * 64 + (((kk * 4 + lg) ^ (row & 7)) * 8)]);
            }
            #pragma unroll
            for (int n = 0; n < 4; ++n) {
                int row = wn * 64 + n * 16 + lr;
                bfr[n] = *reinterpret_cast<const bf16x8*>(&Bs[row * 64 + (((kk * 4 + lg) ^ (row & 7)) * 8)]);
            }
            #pragma unroll
            for (int m = 0; m < 4; ++m)
                #pragma unroll
                for (int n = 0; n < 4; ++n)
                    acc[m][n] = __builtin_amdgcn_mfma_f32_16x16x32_bf16(af[m], bfr[n], acc[m][n], 0, 0, 0);
        }
    }

    if (z < 2) {
        const float* cs_t = tabs + (z == 0 ? 0 : 1536);
        const float* ss_t = tabs + (z == 0 ? 768 : 2304);
        bf16_t* dst = (z == 0) ? q_ws : k_ws;
        #pragma unroll
        for (int m = 0; m < 4; ++m) {
            #pragma unroll
            for (int n = 0; n < 4; ++n) {
                const int col = bn * 128 + wn * 64 + n * 16 + lr;
                const float bvv = bias[col];
                const int head = col >> 6, d = col & 63;
                const int j = (d & 31) >> 1, half = d >> 5, odd = d & 1;
                #pragma unroll
                for (int r = 0; r < 4; ++r) {
                    const int rowg = bm * 128 + wm * 64 + m * 16 + lg * 4 + r;
                    const int nb = rowg / L, ll = rowg - nb * L;
                    const int y = ll / GS, x = ll - y * GS;
                    const int pos = half ? y : x;
                    float v = acc[m][n][r] + bvv;
                    if (z == 0) v *= 0.125f;
                    float o = __shfl_xor(v, 1);
                    float cs = cs_t[pos * 16 + j], ss = ss_t[pos * 16 + j];
                    float res = odd ? (v * cs + o * ss) : (v * cs - o * ss);
                    dst[((size_t)(nb * NH + head) * L + ll) * HD + d] = (bf16_t)res;
                }
            }
        }
    } else {
        #pragma unroll
        for (int m = 0; m < 4; ++m) {
            const int rowg0 = bm * 128 + wm * 64 + m * 16 + lg * 4;
            const int nb = rowg0 / L, ll0 = rowg0 - nb * L;
            #pragma unroll
            for (int n = 0; n < 4; ++n) {
                const int col = bn * 128 + wn * 64 + n * 16 + lr;
                const float bvv = bias[col];
                const int head = col >> 6, d = col & 63;
                bf16x4 pk;
                #pragma unroll
                for (int r = 0; r < 4; ++r) pk[r] = (bf16_t)(acc[m][n][r] + bvv);
                *reinterpret_cast<bf16x4*>(&vT_ws[((size_t)(nb * NH + head) * HD + d) * L + ll0]) = pk;
            }
        }
    }
}

// ---------------- flash attention: LDS-staged double-buffered K/V, O^T PV ----------
// grid (L/64, BH), 256 threads = 4 waves; wave owns 16 queries; KVBLK = 64.
// LDS 32KB -> 5 blocks/CU = 160KB exactly: ALL 1152 blocks resident (no tail).
__global__ __launch_bounds__(256, 5)
void attn_kernel(const bf16_t* __restrict__ q_ws, const bf16_t* __restrict__ k_ws,
                 const bf16_t* __restrict__ vT_ws, bf16_t* __restrict__ attn_out)
{
    __shared__ bf16_t K_lds[2][64 * 64];   // [l][d], chunk-XOR-swizzled rows (128B)
    __shared__ bf16_t V_lds[2][64 * 64];   // [d][l], chunk-XOR-swizzled rows (128B)
    const int tid = threadIdx.x;
    const int lane = tid & 63, w = tid >> 6;
    const int lr = lane & 15, lg = lane >> 4;
    const int bh = blockIdx.y;
    const int q0 = blockIdx.x * 64 + w * 16;
    const int nb = bh >> 4, head = bh & 15;

    const bf16_t* qb = q_ws + (size_t)bh * L * HD;
    const bf16_t* kb = k_ws + (size_t)bh * L * HD;
    const bf16_t* vb = vT_ws + (size_t)bh * HD * L;

    // staging: wave w covers LDS bytes [w*2048, w*2048+2048) of each 8KB tile.
    const int s0 = w * 128 + lane;
    const int r0 = s0 >> 3, c0 = s0 & 7;
    const int cx = c0 ^ (r0 & 7);
    const bf16_t* kst = kb + r0 * HD + cx * 8;
    const bf16_t* vst = vb + (size_t)r0 * L + cx * 8;

    bf16x8 qf[2];
    qf[0] = *reinterpret_cast<const bf16x8*>(qb + (size_t)(q0 + lr) * HD + lg * 8);
    qf[1] = *reinterpret_cast<const bf16x8*>(qb + (size_t)(q0 + lr) * HD + 32 + lg * 8);

    f32x4 o_acc[4] = {};
    float m_run = -1e30f, l_run = 0.0f;

    gload16(kst,           &K_lds[0][w * 1024]);
    gload16(kst + 512,     &K_lds[0][w * 1024 + 512]);
    gload16(vst,           &V_lds[0][w * 1024]);
    gload16(vst + 8 * L,   &V_lds[0][w * 1024 + 512]);
    __syncthreads();

    int cur = 0;
    constexpr int NT = L / 64;   // 36
    for (int kt = 0; kt < NT; ++kt) {
        if (kt + 1 < NT) {
            const bf16_t* kn = kst + (size_t)(kt + 1) * 4096;
            const bf16_t* vn = vst + (kt + 1) * 64;
            bf16_t* kd = &K_lds[cur ^ 1][w * 1024];
            bf16_t* vd = &V_lds[cur ^ 1][w * 1024];
            gload16(kn,         kd);
            gload16(kn + 512,   kd + 512);
            gload16(vn,         vd);
            gload16(vn + 8 * L, vd + 512);
        }
        // S^T = K Q^T : lane holds S[key = ct*16 + lg*4 + r][q = lr]
        f32x4 s[4];
        __builtin_amdgcn_s_setprio(1);
        #pragma unroll
        for (int ct = 0; ct < 4; ++ct) {
            const int row = ct * 16 + lr;
            bf16x8 kf0 = *reinterpret_cast<const bf16x8*>(&K_lds[cur][row * 64 + ((lg ^ (lr & 7)) * 8)]);
            bf16x8 kf1 = *reinterpret_cast<const bf16x8*>(&K_lds[cur][row * 64 + (((4 + lg) ^ (lr & 7)) * 8)]);
            f32x4 t = {};
            t = __builtin_amdgcn_mfma_f32_16x16x32_bf16(kf0, qf[0], t, 0, 0, 0);
            t = __builtin_amdgcn_mfma_f32_16x16x32_bf16(kf1, qf[1], t, 0, 0, 0);
            s[ct] = t;
        }
        __builtin_amdgcn_s_setprio(0);
        // online softmax with defer-max (T13): skip rescale if max growth <= 8
        f32x4 ma = vmax4(vmax4(s[0], s[1]), vmax4(s[2], s[3]));
        float mt = fmaxf(fmaxf(ma[0], ma[1]), fmaxf(ma[2], ma[3]));
        mt = fmaxf(mt, __shfl_xor(mt, 16));
        mt = fmaxf(mt, __shfl_xor(mt, 32));
        if (!__all(mt <= m_run + 8.0f)) {
            const float mn = fmaxf(m_run, mt);
            const float al = __expf(m_run - mn);
            m_run = mn;
            l_run *= al;
            #pragma unroll
            for (int dt = 0; dt < 4; ++dt) o_acc[dt] *= al;
        }
        #pragma unroll
        for (int ct = 0; ct < 4; ++ct) {
            #pragma unroll
            for (int r = 0; r < 4; ++r) s[ct][r] = __expf(s[ct][r] - m_run);
        }
        f32x4 sa = (s[0] + s[1]) + (s[2] + s[3]);
        float rs = (sa[0] + sa[1]) + (sa[2] + sa[3]);
        rs += __shfl_xor(rs, 16);
        rs += __shfl_xor(rs, 32);
        l_run += rs;
        // pack P rows to bf16 quads: lane (lr,lg) owns key-quad ct*4+lg in pk[ct] (q=lr)
        ull pk[4];
        #pragma unroll
        for (int ct = 0; ct < 4; ++ct) {
            bf16x4 t4;
            t4[0] = (bf16_t)s[ct][0]; t4[1] = (bf16_t)s[ct][1];
            t4[2] = (bf16_t)s[ct][2]; t4[3] = (bf16_t)s[ct][3];
            pk[ct] = *reinterpret_cast<ull*>(&t4);
        }
        // O^T += V^T P : build P B-frags by cross-lane quad gather.
        __builtin_amdgcn_s_setprio(1);
        #pragma unroll
        for (int kk = 0; kk < 2; ++kk) {
            const int bsl = ((lg & 1) << 5) + lr;
            ull a0 = __shfl(pk[kk * 2],     bsl);
            ull a1 = __shfl(pk[kk * 2 + 1], bsl);
            ull b0 = __shfl(pk[kk * 2],     bsl + 16);
            ull b1 = __shfl(pk[kk * 2 + 1], bsl + 16);
            ull lo = (lg & 2) ? a1 : a0;
            ull hi = (lg & 2) ? b1 : b0;
            bf16x8 pa;
            reinterpret_cast<ull*>(&pa)[0] = lo;
            reinterpret_cast<ull*>(&pa)[1] = hi;
            #pragma unroll
            for (int dt = 0; dt < 4; ++dt) {
                const int row = dt * 16 + lr;
                bf16x8 vf = *reinterpret_cast<const bf16x8*>(
                    &V_lds[cur][row * 64 + (((kk * 4 + lg) ^ (lr & 7)) * 8)]);
                o_acc[dt] = __builtin_amdgcn_mfma_f32_16x16x32_bf16(vf, pa, o_acc[dt], 0, 0, 0);
            }
        }
        __builtin_amdgcn_s_setprio(0);
        __syncthreads();
        cur ^= 1;
    }

    const float inv = 1.0f / l_run;
    #pragma unroll
    for (int dt = 0; dt < 4; ++dt) {
        bf16x4 o;
        #pragma unroll
        for (int r = 0; r < 4; ++r) o[r] = (bf16_t)(o_acc[dt][r] * inv);
        *reinterpret_cast<bf16x4*>(
            &attn_out[(size_t)(nb * L + q0 + lr) * E + head * HD + dt * 16 + lg * 4]) = o;
    }
}

// ---------------- output projection GEMM (A bf16, W bf16, both async-staged) ------
__global__ __launch_bounds__(256, 3)
void out_gemm_kernel(const bf16_t* __restrict__ A, const bf16_t* __restrict__ Wb,
                     const float* __restrict__ bias, float* __restrict__ outp)
{
    __shared__ bf16_t As[128 * 64];
    __shared__ bf16_t Bs[128 * 64];
    const int tid = threadIdx.x;
    const int lane = tid & 63;
    const int wv = tid >> 6;
    const int wm = wv >> 1, wn = wv & 1;
    const int lr = lane & 15, lg = lane >> 4;
    const int bm = blockIdx.x, bn = blockIdx.y;

    f32x4 acc[4][4] = {};

    for (int kt = 0; kt < E / 64; ++kt) {
        const int k0 = kt * 64;
        __syncthreads();
        const bf16_t* Abase = A  + (size_t)(bm * 128) * E + k0;
        const bf16_t* Wbase = Wb + (size_t)(bn * 128) * E + k0;
        #pragma unroll
        for (int it = 0; it < 4; ++it) {
            int s = it * 256 + tid;
            int r = s >> 3, c = s & 7;
            const int off = (c ^ (r & 7)) * 8;
            gload16(Abase + (size_t)r * E + off, (char*)As + it * 4096 + wv * 1024);
            gload16(Wbase + (size_t)r * E + off, (char*)Bs + it * 4096 + wv * 1024);
        }
        __syncthreads();
        #pragma unroll
        for (int kk = 0; kk < 2; ++kk) {
            bf16x8 af[4], bfr[4];
            #pragma unroll
            for (int m = 0; m < 4; ++m) {
                int row = wm * 64 + m * 16 + lr;
                af[m] = *reinterpret_cast<const bf16x8*>(&As[row * 64 + (((kk * 4 + lg) ^ (row & 7)) * 8)]);
            }
            #pragma unroll
            for (int n = 0; n < 4; ++n) {
                int row = wn * 64 + n * 16 + lr;
                bfr[n] = *reinterpret_cast<const bf16x8*>(&Bs[row * 64 + (((kk * 4 + lg) ^ (row & 7)) * 8)]);
            }
            #pragma unroll
            for (int m = 0; m < 4; ++m)
                #pragma unroll
                for (int n = 0; n < 4; ++n)
                    acc[m][n] = __builtin_amdgcn_mfma_f32_16x16x32_bf16(af[m], bfr[n], acc[m][n], 0, 0, 0);
        }
    }

    #pragma unroll
    for (int m = 0; m < 4; ++m) {
        #pragma unroll
        for (int n = 0; n < 4; ++n) {
            const int col = bn * 128 + wn * 64 + n * 16 + lr;
            const float bvv = bias[col];
            #pragma unroll
            for (int r = 0; r < 4; ++r) {
                const int rowg = bm * 128 + wm * 64 + m * 16 + lg * 4 + r;
                outp[(size_t)rowg * E + col] = acc[m][n][r] + bvv;
            }
        }
    }
}

// ---------------- launch ----------------
extern "C" void kernel_launch(void* const* d_in, const int* in_sizes, int n_in,
                              void* d_out, int out_size, void* d_ws, size_t ws_size,
                              hipStream_t stream)
{
    const float* query = (const float*)d_in[0];
    const float* key   = (const float*)d_in[1];
    const float* value = (const float*)d_in[2];
    const float* Wq = (const float*)d_in[3];
    const float* bq = (const float*)d_in[4];
    const float* Wk = (const float*)d_in[5];
    const float* bk = (const float*)d_in[6];
    const float* Wv = (const float*)d_in[7];
    const float* bv = (const float*)d_in[8];
    const float* Wo = (const float*)d_in[9];
    const float* bo = (const float*)d_in[10];

    char* ws = (char*)d_ws;
    constexpr size_t QKV_BYTES = (size_t)BH * L * HD * sizeof(bf16_t);  // 9437184
    constexpr size_t W_BYTES   = (size_t)E * E * sizeof(bf16_t);        // 2097152
    float*  tabs    = (float*)(ws);
    bf16_t* q_ws    = (bf16_t*)(ws + 16384);
    bf16_t* k_ws    = (bf16_t*)(ws + 16384 + 1 * QKV_BYTES);
    bf16_t* vT_ws   = (bf16_t*)(ws + 16384 + 2 * QKV_BYTES);
    bf16_t* attn_ws = (bf16_t*)(ws + 16384 + 3 * QKV_BYTES);
    bf16_t* Wq_b    = (bf16_t*)(ws + 16384 + 4 * QKV_BYTES);
    bf16_t* Wk_b    = (bf16_t*)(ws + 16384 + 4 * QKV_BYTES + 1 * W_BYTES);
    bf16_t* Wv_b    = (bf16_t*)(ws + 16384 + 4 * QKV_BYTES + 2 * W_BYTES);
    bf16_t* Wo_b    = (bf16_t*)(ws + 16384 + 4 * QKV_BYTES + 3 * W_BYTES);

    prep_kernel<<<1024, 256, 0, stream>>>(Wq, Wk, Wv, Wo, Wq_b, Wk_b, Wv_b, Wo_b, tabs);

    qkv_gemm_kernel<<<dim3(T / 128, E / 128, 3), 256, 0, stream>>>(
        query, key, value, Wq_b, Wk_b, Wv_b, bq, bk, bv, q_ws, k_ws, vT_ws, tabs);

    attn_kernel<<<dim3(L / 64, BH), 256, 0, stream>>>(q_ws, k_ws, vT_ws, attn_ws);

    out_gemm_kernel<<<dim3(T / 128, E / 128), 256, 0, stream>>>(attn_ws, Wo_b, bo, (float*)d_out);
}

// Round 7
// 166.928 us; speedup vs baseline: 2.8225x; 1.1344x over previous
//
#include <hip/hip_runtime.h>
#include <hip/hip_bf16.h>

typedef __bf16 bf16_t;
typedef __bf16 bf16x4 __attribute__((ext_vector_type(4)));
typedef __bf16 bf16x8 __attribute__((ext_vector_type(8)));
typedef float f32x4 __attribute__((ext_vector_type(4)));
typedef unsigned int u32;
typedef u32 u32x4 __attribute__((ext_vector_type(4)));

constexpr int E  = 1024;
constexpr int NH = 16;
constexpr int HD = 64;
constexpr int NB = 2;
constexpr int GS = 48;          // spatial side
constexpr int L  = GS * GS;     // 2304 tokens per batch
constexpr int T  = NB * L;      // 4608 tokens
constexpr int BH = NB * NH;     // 32 batch*head

static __device__ __forceinline__ f32x4 vmax4(f32x4 a, f32x4 b) {
    f32x4 r;
    r[0] = fmaxf(a[0], b[0]); r[1] = fmaxf(a[1], b[1]);
    r[2] = fmaxf(a[2], b[2]); r[3] = fmaxf(a[3], b[3]);
    return r;
}

static __device__ __forceinline__ void gload16(const void* g, void* l) {
    __builtin_amdgcn_global_load_lds(
        (const __attribute__((address_space(1))) unsigned int*)g,
        (__attribute__((address_space(3))) unsigned int*)l, 16, 0, 0);
}

// cross-half reduces via permlane-swap BUILTINS (hazards handled by compiler)
static __device__ __forceinline__ float redmax16(float x) {
    u32 a = __builtin_bit_cast(u32, x);
    auto r = __builtin_amdgcn_permlane16_swap(a, a, false, false);
    return fmaxf(__builtin_bit_cast(float, r[0]), __builtin_bit_cast(float, r[1]));
}
static __device__ __forceinline__ float redmax32(float x) {
    u32 a = __builtin_bit_cast(u32, x);
    auto r = __builtin_amdgcn_permlane32_swap(a, a, false, false);
    return fmaxf(__builtin_bit_cast(float, r[0]), __builtin_bit_cast(float, r[1]));
}
static __device__ __forceinline__ float redadd16(float x) {
    u32 a = __builtin_bit_cast(u32, x);
    auto r = __builtin_amdgcn_permlane16_swap(a, a, false, false);
    return __builtin_bit_cast(float, r[0]) + __builtin_bit_cast(float, r[1]);
}
static __device__ __forceinline__ float redadd32(float x) {
    u32 a = __builtin_bit_cast(u32, x);
    auto r = __builtin_amdgcn_permlane32_swap(a, a, false, false);
    return __builtin_bit_cast(float, r[0]) + __builtin_bit_cast(float, r[1]);
}
static __device__ __forceinline__ u32 cvtpk(float lo, float hi) {
    u32 r;
    asm("v_cvt_pk_bf16_f32 %0, %1, %2" : "=v"(r) : "v"(lo), "v"(hi));
    return r;
}

// ------- prep: cast Wq/Wk/Wv/Wo to bf16 (+ xpos tables in block 0) -------------
__global__ __launch_bounds__(256)
void prep_kernel(const float* __restrict__ Wq, const float* __restrict__ Wk,
                 const float* __restrict__ Wv, const float* __restrict__ Wo,
                 bf16_t* __restrict__ Wq_b, bf16_t* __restrict__ Wk_b,
                 bf16_t* __restrict__ Wv_b, bf16_t* __restrict__ Wo_b,
                 float* __restrict__ tabs)
{
    if (blockIdx.x == 0) {
        #pragma unroll
        for (int j = 0; j < 3; ++j) {
            int i = threadIdx.x + 256 * j;           // 0..767
            int p = i >> 4, jj = i & 15;
            float sv = (2.0f * (float)jj + 12.8f) / 44.8f;
            float pw = ((float)p - 24.0f) / 512.0f;
            float scale = powf(sv, pw);
            float inv_freq = powf(10000.0f, -(float)jj / 16.0f);
            float ang = (float)p * inv_freq;
            float s = sinf(ang), c = cosf(ang);
            tabs[0 * 768 + i] = c * scale;   // q: downscale=False
            tabs[1 * 768 + i] = s * scale;
            tabs[2 * 768 + i] = c / scale;   // k: downscale=True
            tabs[3 * 768 + i] = s / scale;
        }
    }
    const int gid = blockIdx.x * 256 + threadIdx.x;
    const float* srcs[4] = {Wq, Wk, Wv, Wo};
    bf16_t* dsts[4] = {Wq_b, Wk_b, Wv_b, Wo_b};
    #pragma unroll
    for (int wsel = 0; wsel < 4; ++wsel) {
        f32x4 v = *reinterpret_cast<const f32x4*>(srcs[wsel] + (size_t)gid * 4);
        bf16x4 o;
        o[0] = (bf16_t)v[0]; o[1] = (bf16_t)v[1]; o[2] = (bf16_t)v[2]; o[3] = (bf16_t)v[3];
        *reinterpret_cast<bf16x4*>(dsts[wsel] + (size_t)gid * 4) = o;
    }
}

// ---------------- fused QKV GEMM (z = 0:Q+xpos, 1:K+xpos, 2:V transposed) ----------
__global__ __launch_bounds__(256, 3)
void qkv_gemm_kernel(const float* __restrict__ Aq, const float* __restrict__ Ak,
                     const float* __restrict__ Av,
                     const bf16_t* __restrict__ Wqb, const bf16_t* __restrict__ Wkb,
                     const bf16_t* __restrict__ Wvb,
                     const float* __restrict__ bq, const float* __restrict__ bk,
                     const float* __restrict__ bv,
                     bf16_t* __restrict__ q_ws, bf16_t* __restrict__ k_ws,
                     bf16_t* __restrict__ vT_ws, const float* __restrict__ tabs)
{
    __shared__ bf16_t As[128 * 64];
    __shared__ bf16_t Bs[128 * 64];
    const int z = blockIdx.z;
    const float*  A    = (z == 0) ? Aq  : (z == 1) ? Ak  : Av;
    const bf16_t* Wb   = (z == 0) ? Wqb : (z == 1) ? Wkb : Wvb;
    const float*  bias = (z == 0) ? bq  : (z == 1) ? bk  : bv;

    const int tid = threadIdx.x;
    const int lane = tid & 63;
    const int wv = tid >> 6;
    const int wm = wv >> 1, wn = wv & 1;
    const int lr = lane & 15, lg = lane >> 4;
    const int bm = blockIdx.x, bn = blockIdx.y;

    f32x4 acc[4][4] = {};

    for (int kt = 0; kt < E / 64; ++kt) {
        const int k0 = kt * 64;
        __syncthreads();
        const bf16_t* Wbase = Wb + (size_t)(bn * 128) * E + k0;
        #pragma unroll
        for (int it = 0; it < 4; ++it) {
            int s = it * 256 + tid;
            int r = s >> 3, c = s & 7;
            gload16(Wbase + (size_t)r * E + ((c ^ (r & 7)) * 8),
                    (char*)Bs + it * 4096 + wv * 1024);
        }
        #pragma unroll
        for (int it = 0; it < 4; ++it) {
            int ci = it * 256 + tid;
            int row = ci >> 3, c = ci & 7;
            int sw = ((c ^ (row & 7)) * 8);
            const float* srcA = A + (size_t)(bm * 128 + row) * E + k0 + c * 8;
            f32x4 a0 = *reinterpret_cast<const f32x4*>(srcA);
            f32x4 a1 = *reinterpret_cast<const f32x4*>(srcA + 4);
            bf16x8 ha;
            ha[0] = (bf16_t)a0[0]; ha[1] = (bf16_t)a0[1]; ha[2] = (bf16_t)a0[2]; ha[3] = (bf16_t)a0[3];
            ha[4] = (bf16_t)a1[0]; ha[5] = (bf16_t)a1[1]; ha[6] = (bf16_t)a1[2]; ha[7] = (bf16_t)a1[3];
            *reinterpret_cast<bf16x8*>(&As[row * 64 + sw]) = ha;
        }
        __syncthreads();
        #pragma unroll
        for (int kk = 0; kk < 2; ++kk) {
            bf16x8 af[4], bfr[4];
            #pragma unroll
            for (int m = 0; m < 4; ++m) {
                int row = wm * 64 + m * 16 + lr;
                af[m] = *reinterpret_cast<const bf16x8*>(&As[row * 64 + (((kk * 4 + lg) ^ (row & 7)) * 8)]);
            }
            #pragma unroll
            for (int n = 0; n < 4; ++n) {
                int row = wn * 64 + n * 16 + lr;
                bfr[n] = *reinterpret_cast<const bf16x8*>(&Bs[row * 64 + (((kk * 4 + lg) ^ (row & 7)) * 8)]);
            }
            #pragma unroll
            for (int m = 0; m < 4; ++m)
                #pragma unroll
                for (int n = 0; n < 4; ++n)
                    acc[m][n] = __builtin_amdgcn_mfma_f32_16x16x32_bf16(af[m], bfr[n], acc[m][n], 0, 0, 0);
        }
    }

    if (z < 2) {
        const float* cs_t = tabs + (z == 0 ? 0 : 1536);
        const float* ss_t = tabs + (z == 0 ? 768 : 2304);
        bf16_t* dst = (z == 0) ? q_ws : k_ws;
        #pragma unroll
        for (int m = 0; m < 4; ++m) {
            #pragma unroll
            for (int n = 0; n < 4; ++n) {
                const int col = bn * 128 + wn * 64 + n * 16 + lr;
                const float bvv = bias[col];
                const int head = col >> 6, d = col & 63;
                const int j = (d & 31) >> 1, half = d >> 5, odd = d & 1;
                #pragma unroll
                for (int r = 0; r < 4; ++r) {
                    const int rowg = bm * 128 + wm * 64 + m * 16 + lg * 4 + r;
                    const int nb = rowg / L, ll = rowg - nb * L;
                    const int y = ll / GS, x = ll - y * GS;
                    const int pos = half ? y : x;
                    float v = acc[m][n][r] + bvv;
                    if (z == 0) v *= 0.125f;
                    float o = __shfl_xor(v, 1);
                    float cs = cs_t[pos * 16 + j], ss = ss_t[pos * 16 + j];
                    float res = odd ? (v * cs + o * ss) : (v * cs - o * ss);
                    dst[((size_t)(nb * NH + head) * L + ll) * HD + d] = (bf16_t)res;
                }
            }
        }
    } else {
        #pragma unroll
        for (int m = 0; m < 4; ++m) {
            const int rowg0 = bm * 128 + wm * 64 + m * 16 + lg * 4;
            const int nb = rowg0 / L, ll0 = rowg0 - nb * L;
            #pragma unroll
            for (int n = 0; n < 4; ++n) {
                const int col = bn * 128 + wn * 64 + n * 16 + lr;
                const float bvv = bias[col];
                const int head = col >> 6, d = col & 63;
                bf16x4 pk;
                #pragma unroll
                for (int r = 0; r < 4; ++r) pk[r] = (bf16_t)(acc[m][n][r] + bvv);
                *reinterpret_cast<bf16x4*>(&vT_ws[((size_t)(nb * NH + head) * HD + d) * L + ll0]) = pk;
            }
        }
    }
}

// ---------------- flash attention: LDS K/V dbuf, permlane P-gather (no bpermute) ---
// grid (L/64, BH), 256 threads = 4 waves; wave owns 16 queries; KVBLK = 64.
__global__ __launch_bounds__(256, 5)
void attn_kernel(const bf16_t* __restrict__ q_ws, const bf16_t* __restrict__ k_ws,
                 const bf16_t* __restrict__ vT_ws, bf16_t* __restrict__ attn_out)
{
    __shared__ bf16_t K_lds[2][64 * 64];   // [l][d], chunk-XOR-swizzled rows (128B)
    __shared__ bf16_t V_lds[2][64 * 64];   // [d][l], chunk-XOR-swizzled rows (128B)
    const int tid = threadIdx.x;
    const int lane = tid & 63, w = tid >> 6;
    const int lr = lane & 15, lg = lane >> 4;
    const int bh = blockIdx.y;
    const int q0 = blockIdx.x * 64 + w * 16;
    const int nb = bh >> 4, head = bh & 15;

    const bf16_t* qb = q_ws + (size_t)bh * L * HD;
    const bf16_t* kb = k_ws + (size_t)bh * L * HD;
    const bf16_t* vb = vT_ws + (size_t)bh * HD * L;

    const int s0 = w * 128 + lane;
    const int r0 = s0 >> 3, c0 = s0 & 7;
    const int cx = c0 ^ (r0 & 7);
    const bf16_t* kst = kb + r0 * HD + cx * 8;
    const bf16_t* vst = vb + (size_t)r0 * L + cx * 8;

    bf16x8 qf[2];
    qf[0] = *reinterpret_cast<const bf16x8*>(qb + (size_t)(q0 + lr) * HD + lg * 8);
    qf[1] = *reinterpret_cast<const bf16x8*>(qb + (size_t)(q0 + lr) * HD + 32 + lg * 8);

    f32x4 o_acc[4] = {};
    float m_run = -1e30f, l_run = 0.0f;

    gload16(kst,           &K_lds[0][w * 1024]);
    gload16(kst + 512,     &K_lds[0][w * 1024 + 512]);
    gload16(vst,           &V_lds[0][w * 1024]);
    gload16(vst + 8 * L,   &V_lds[0][w * 1024 + 512]);
    __syncthreads();

    int cur = 0;
    constexpr int NT = L / 64;   // 36
    for (int kt = 0; kt < NT; ++kt) {
        if (kt + 1 < NT) {
            const bf16_t* kn = kst + (size_t)(kt + 1) * 4096;
            const bf16_t* vn = vst + (kt + 1) * 64;
            bf16_t* kd = &K_lds[cur ^ 1][w * 1024];
            bf16_t* vd = &V_lds[cur ^ 1][w * 1024];
            gload16(kn,         kd);
            gload16(kn + 512,   kd + 512);
            gload16(vn,         vd);
            gload16(vn + 8 * L, vd + 512);
        }
        // S^T = K Q^T : lane holds S[key = ct*16 + lg*4 + r][q = lr]
        f32x4 s[4];
        __builtin_amdgcn_s_setprio(1);
        #pragma unroll
        for (int ct = 0; ct < 4; ++ct) {
            const int row = ct * 16 + lr;
            bf16x8 kf0 = *reinterpret_cast<const bf16x8*>(&K_lds[cur][row * 64 + ((lg ^ (lr & 7)) * 8)]);
            bf16x8 kf1 = *reinterpret_cast<const bf16x8*>(&K_lds[cur][row * 64 + (((4 + lg) ^ (lr & 7)) * 8)]);
            f32x4 t = {};
            t = __builtin_amdgcn_mfma_f32_16x16x32_bf16(kf0, qf[0], t, 0, 0, 0);
            t = __builtin_amdgcn_mfma_f32_16x16x32_bf16(kf1, qf[1], t, 0, 0, 0);
            s[ct] = t;
        }
        __builtin_amdgcn_s_setprio(0);
        // online softmax with defer-max; reduces via permlane swaps (VALU only)
        f32x4 ma = vmax4(vmax4(s[0], s[1]), vmax4(s[2], s[3]));
        float mt = fmaxf(fmaxf(ma[0], ma[1]), fmaxf(ma[2], ma[3]));
        mt = redmax16(mt);
        mt = redmax32(mt);
        if (!__all(mt <= m_run + 8.0f)) {
            const float mn = fmaxf(m_run, mt);
            const float al = __expf(m_run - mn);
            m_run = mn;
            l_run *= al;
            #pragma unroll
            for (int dt = 0; dt < 4; ++dt) o_acc[dt] *= al;
        }
        #pragma unroll
        for (int ct = 0; ct < 4; ++ct) {
            #pragma unroll
            for (int r = 0; r < 4; ++r) s[ct][r] = __expf(s[ct][r] - m_run);
        }
        f32x4 sa = (s[0] + s[1]) + (s[2] + s[3]);
        float rs = (sa[0] + sa[1]) + (sa[2] + sa[3]);
        rs = redadd16(rs);
        rs = redadd32(rs);
        l_run += rs;
        // pack P to bf16 pairs: c01/c23[ct] = keys (16ct + 4*lg + {0,1}/{2,3}) for q = lr
        u32 c01[4], c23[4];
        #pragma unroll
        for (int ct = 0; ct < 4; ++ct) {
            c01[ct] = cvtpk(s[ct][0], s[ct][1]);
            c23[ct] = cvtpk(s[ct][2], s[ct][3]);
        }
        // O^T += V^T P : assemble B-frags in-register via permlane-swap builtins.
        // pl32(X,Y) -> {A1,A2}; pl16(A1,A2) -> {word_lo, word_hi}
        __builtin_amdgcn_s_setprio(1);
        #pragma unroll
        for (int kk = 0; kk < 2; ++kk) {
            auto p1 = __builtin_amdgcn_permlane32_swap(c01[kk * 2], c01[kk * 2 + 1], false, false);
            auto p2 = __builtin_amdgcn_permlane16_swap(p1[0], p1[1], false, false);
            auto p3 = __builtin_amdgcn_permlane32_swap(c23[kk * 2], c23[kk * 2 + 1], false, false);
            auto p4 = __builtin_amdgcn_permlane16_swap(p3[0], p3[1], false, false);
            u32x4 paw;
            paw[0] = p2[0]; paw[1] = p4[0]; paw[2] = p2[1]; paw[3] = p4[1];
            bf16x8 pa = __builtin_bit_cast(bf16x8, paw);
            #pragma unroll
            for (int dt = 0; dt < 4; ++dt) {
                const int row = dt * 16 + lr;
                bf16x8 vf = *reinterpret_cast<const bf16x8*>(
                    &V_lds[cur][row * 64 + (((kk * 4 + lg) ^ (lr & 7)) * 8)]);
                o_acc[dt] = __builtin_amdgcn_mfma_f32_16x16x32_bf16(vf, pa, o_acc[dt], 0, 0, 0);
            }
        }
        __builtin_amdgcn_s_setprio(0);
        __syncthreads();
        cur ^= 1;
    }

    const float inv = 1.0f / l_run;
    #pragma unroll
    for (int dt = 0; dt < 4; ++dt) {
        bf16x4 o;
        #pragma unroll
        for (int r = 0; r < 4; ++r) o[r] = (bf16_t)(o_acc[dt][r] * inv);
        *reinterpret_cast<bf16x4*>(
            &attn_out[(size_t)(nb * L + q0 + lr) * E + head * HD + dt * 16 + lg * 4]) = o;
    }
}

// ---------------- output projection GEMM (A bf16, W bf16, both async-staged) ------
__global__ __launch_bounds__(256, 3)
void out_gemm_kernel(const bf16_t* __restrict__ A, const bf16_t* __restrict__ Wb,
                     const float* __restrict__ bias, float* __restrict__ outp)
{
    __shared__ bf16_t As[128 * 64];
    __shared__ bf16_t Bs[128 * 64];
    const int tid = threadIdx.x;
    const int lane = tid & 63;
    const int wv = tid >> 6;
    const int wm = wv >> 1, wn = wv & 1;
    const int lr = lane & 15, lg = lane >> 4;
    const int bm = blockIdx.x, bn = blockIdx.y;

    f32x4 acc[4][4] = {};

    for (int kt = 0; kt < E / 64; ++kt) {
        const int k0 = kt * 64;
        __syncthreads();
        const bf16_t* Abase = A  + (size_t)(bm * 128) * E + k0;
        const bf16_t* Wbase = Wb + (size_t)(bn * 128) * E + k0;
        #pragma unroll
        for (int it = 0; it < 4; ++it) {
            int s = it * 256 + tid;
            int r = s >> 3, c = s & 7;
            const int off = (c ^ (r & 7)) * 8;
            gload16(Abase + (size_t)r * E + off, (char*)As + it * 4096 + wv * 1024);
            gload16(Wbase + (size_t)r * E + off, (char*)Bs + it * 4096 + wv * 1024);
        }
        __syncthreads();
        #pragma unroll
        for (int kk = 0; kk < 2; ++kk) {
            bf16x8 af[4], bfr[4];
            #pragma unroll
            for (int m = 0; m < 4; ++m) {
                int row = wm * 64 + m * 16 + lr;
                af[m] = *reinterpret_cast<const bf16x8*>(&As[row * 64 + (((kk * 4 + lg) ^ (row & 7)) * 8)]);
            }
            #pragma unroll
            for (int n = 0; n < 4; ++n) {
                int row = wn * 64 + n * 16 + lr;
                bfr[n] = *reinterpret_cast<const bf16x8*>(&Bs[row * 64 + (((kk * 4 + lg) ^ (row & 7)) * 8)]);
            }
            #pragma unroll
            for (int m = 0; m < 4; ++m)
                #pragma unroll
                for (int n = 0; n < 4; ++n)
                    acc[m][n] = __builtin_amdgcn_mfma_f32_16x16x32_bf16(af[m], bfr[n], acc[m][n], 0, 0, 0);
        }
    }

    #pragma unroll
    for (int m = 0; m < 4; ++m) {
        #pragma unroll
        for (int n = 0; n < 4; ++n) {
            const int col = bn * 128 + wn * 64 + n * 16 + lr;
            const float bvv = bias[col];
            #pragma unroll
            for (int r = 0; r < 4; ++r) {
                const int rowg = bm * 128 + wm * 64 + m * 16 + lg * 4 + r;
                outp[(size_t)rowg * E + col] = acc[m][n][r] + bvv;
            }
        }
    }
}

// ---------------- launch ----------------
extern "C" void kernel_launch(void* const* d_in, const int* in_sizes, int n_in,
                              void* d_out, int out_size, void* d_ws, size_t ws_size,
                              hipStream_t stream)
{
    const float* query = (const float*)d_in[0];
    const float* key   = (const float*)d_in[1];
    const float* value = (const float*)d_in[2];
    const float* Wq = (const float*)d_in[3];
    const float* bq = (const float*)d_in[4];
    const float* Wk = (const float*)d_in[5];
    const float* bk = (const float*)d_in[6];
    const float* Wv = (const float*)d_in[7];
    const float* bv = (const float*)d_in[8];
    const float* Wo = (const float*)d_in[9];
    const float* bo = (const float*)d_in[10];

    char* ws = (char*)d_ws;
    constexpr size_t QKV_BYTES = (size_t)BH * L * HD * sizeof(bf16_t);  // 9437184
    constexpr size_t W_BYTES   = (size_t)E * E * sizeof(bf16_t);        // 2097152
    float*  tabs    = (float*)(ws);
    bf16_t* q_ws    = (bf16_t*)(ws + 16384);
    bf16_t* k_ws    = (bf16_t*)(ws + 16384 + 1 * QKV_BYTES);
    bf16_t* vT_ws   = (bf16_t*)(ws + 16384 + 2 * QKV_BYTES);
    bf16_t* attn_ws = (bf16_t*)(ws + 16384 + 3 * QKV_BYTES);
    bf16_t* Wq_b    = (bf16_t*)(ws + 16384 + 4 * QKV_BYTES);
    bf16_t* Wk_b    = (bf16_t*)(ws + 16384 + 4 * QKV_BYTES + 1 * W_BYTES);
    bf16_t* Wv_b    = (bf16_t*)(ws + 16384 + 4 * QKV_BYTES + 2 * W_BYTES);
    bf16_t* Wo_b    = (bf16_t*)(ws + 16384 + 4 * QKV_BYTES + 3 * W_BYTES);

    prep_kernel<<<1024, 256, 0, stream>>>(Wq, Wk, Wv, Wo, Wq_b, Wk_b, Wv_b, Wo_b, tabs);

    qkv_gemm_kernel<<<dim3(T / 128, E / 128, 3), 256, 0, stream>>>(
        query, key, value, Wq_b, Wk_b, Wv_b, bq, bk, bv, q_ws, k_ws, vT_ws, tabs);

    attn_kernel<<<dim3(L / 64, BH), 256, 0, stream>>>(q_ws, k_ws, vT_ws, attn_ws);

    out_gemm_kernel<<<dim3(T / 128, E / 128), 256, 0, stream>>>(attn_ws, Wo_b, bo, (float*)d_out);
}